// Round 6
// baseline (772.682 us; speedup 1.0000x reference)
//
#include <hip/hip_runtime.h>
#include <hip/hip_bf16.h>
#include <math.h>

typedef __bf16 bf16_t;
typedef __bf16 bf16x4 __attribute__((ext_vector_type(4)));
typedef __bf16 bf16x8 __attribute__((ext_vector_type(8)));
typedef float f32x4 __attribute__((ext_vector_type(4)));
typedef float f32x2 __attribute__((ext_vector_type(2)));

static constexpr int N_NODES = 32768;
static constexpr int N_EDGES = N_NODES * 16;

#define GLB_PTR(p) ((const __attribute__((address_space(1))) void*)(p))
#define LDS_PTR(p) ((__attribute__((address_space(3))) void*)(p))

// flag per tensor: 0 = fp32, 1 = bf16, 2 = all-zero (return 0 without reading)
__device__ __forceinline__ float load_ext(const void* p, long i, int fl) {
  if (fl == 2) return 0.f;
  return fl ? (float)((const bf16_t*)p)[i] : ((const float*)p)[i];
}

// ---------------------------------------------------------------------------
// Per-tensor dtype sniffer. kind 0 = float tensor, kind 1 = int tensor.
// ---------------------------------------------------------------------------
struct SniffArgs {
  const void* ptr[20];
  int elems[20];
  int kind[20];
};

__global__ __launch_bounds__(256) void sniff_all(SniffArgs a, int* flags) {
  int b = blockIdx.x;
  int t = threadIdx.x;
  __shared__ int s1[256], s2[256];
  if (a.kind[b] == 0) {
    const unsigned short* p = (const unsigned short*)a.ptr[b];
    int pairs = min(1024, a.elems[b] / 2);
    int sane = 0, nz = 0;
    for (int i = t; i < pairs; i += 256) {
      unsigned short we = p[2 * i], wo = p[2 * i + 1];
      if (we | wo) nz++;
      int e = (we >> 7) & 0xFF;
      if (we != 0 && e >= 100 && e <= 140) sane++;
    }
    s1[t] = sane; s2[t] = nz;
    __syncthreads();
    for (int o = 128; o >= 1; o >>= 1) {
      if (t < o) { s1[t] += s1[t + o]; s2[t] += s2[t + o]; }
      __syncthreads();
    }
    if (t == 0)
      flags[b] = (s2[0] == 0) ? 2 : ((2 * s1[0] > pairs) ? 1 : 0);
  } else {
    const int* ip = (const int*)a.ptr[b];
    int n = min(512, a.elems[b] / 2);
    int zeros = 0;
    for (int i = t; i < n; i += 256)
      if (ip[2 * i + 1] == 0) zeros++;
    s1[t] = zeros;
    __syncthreads();
    for (int o = 128; o >= 1; o >>= 1) {
      if (t < o) s1[t] += s1[t + o];
      __syncthreads();
    }
    if (t == 0) flags[b] = (s1[0] * 4 > n * 3) ? 1 : 0;
  }
}

__global__ __launch_bounds__(256) void convert_x(const void* src, bf16_t* dst,
                                                 const int* flagp) {
  int fl = *flagp;
  int i = (blockIdx.x * 256 + threadIdx.x) * 4;
  if (fl == 1) {
    *(int2*)(dst + i) = *(const int2*)((const bf16_t*)src + i);
  } else if (fl == 0) {
    float4 v = *(const float4*)((const float*)src + i);
    dst[i] = (bf16_t)v.x; dst[i + 1] = (bf16_t)v.y;
    dst[i + 2] = (bf16_t)v.z; dst[i + 3] = (bf16_t)v.w;
  } else {
    dst[i] = (bf16_t)0.f; dst[i + 1] = (bf16_t)0.f;
    dst[i + 2] = (bf16_t)0.f; dst[i + 3] = (bf16_t)0.f;
  }
}

// ---------------------------------------------------------------------------
// Batched 32x32 tile transpose: dst[n*K+k] = src[k*N+n], per-desc dtype flag.
// ---------------------------------------------------------------------------
struct TransDesc { const void* src; long soff; bf16_t* dst; int K; int N; int tile0; int fidx; };
struct TransArgs { TransDesc d[13]; const int* flags; };

__global__ __launch_bounds__(256) void transpose_many(TransArgs args) {
  __shared__ bf16_t tile[32][33];
  int blk = blockIdx.x;
  int i = 0;
#pragma unroll
  for (int j = 1; j < 13; ++j)
    if (blk >= args.d[j].tile0) i = j;
  TransDesc dd = args.d[i];
  int fl = args.flags[dd.fidx];
  int t = blk - dd.tile0;
  int tiles_x = dd.N / 32;
  int nbase = (t % tiles_x) * 32;
  int kbase = (t / tiles_x) * 32;
  int tx = threadIdx.x & 31, ty = threadIdx.x >> 5;
#pragma unroll
  for (int j = 0; j < 32; j += 8)
    tile[ty + j][tx] = (bf16_t)load_ext(dd.src, dd.soff + (long)(kbase + ty + j) * dd.N + nbase + tx, fl);
  __syncthreads();
#pragma unroll
  for (int j = 0; j < 32; j += 8)
    dd.dst[(size_t)(nbase + ty + j) * dd.K + kbase + tx] = tile[tx][ty + j];
}

// ---------------------------------------------------------------------------
// CSR build (edge_index int32 or int64 per flags[1])
// ---------------------------------------------------------------------------
__device__ __forceinline__ int edge_at(const void* ei, long i, int fl64) {
  return fl64 ? (int)((const long long*)ei)[i] : ((const int*)ei)[i];
}

__global__ __launch_bounds__(256) void deg_count(const void* __restrict__ ei,
                                                 const int* flagp,
                                                 int* __restrict__ deg) {
  int fl = *flagp;
  int e = blockIdx.x * 256 + threadIdx.x;
  if (e < N_EDGES) atomicAdd(&deg[edge_at(ei, (long)N_EDGES + e, fl)], 1);
}

__global__ __launch_bounds__(1024) void scan_offsets(const int* __restrict__ deg,
                                                     int* __restrict__ off) {
  __shared__ int s[1024];
  int t = threadIdx.x;
  int base = t * 32;
  int sum = 0;
  for (int i = 0; i < 32; ++i) sum += deg[base + i];
  s[t] = sum;
  __syncthreads();
  for (int o = 1; o < 1024; o <<= 1) {
    int v = (t >= o) ? s[t - o] : 0;
    __syncthreads();
    s[t] += v;
    __syncthreads();
  }
  int run = s[t] - sum;
  for (int i = 0; i < 32; ++i) { off[base + i] = run; run += deg[base + i]; }
  if (t == 1023) off[N_NODES] = run;
}

__global__ __launch_bounds__(256) void scatter_edges(const void* __restrict__ ei,
                                                     const int* flagp,
                                                     const int* __restrict__ off,
                                                     int* __restrict__ cursor,
                                                     int* __restrict__ csr) {
  int fl = *flagp;
  int e = blockIdx.x * 256 + threadIdx.x;
  if (e < N_EDGES) {
    int d = edge_at(ei, (long)N_EDGES + e, fl);
    int p = off[d] + atomicAdd(&cursor[d], 1);
    csr[p] = edge_at(ei, e, fl);
  }
}

// ---------------------------------------------------------------------------
// Attention v6: fp8 q/k/v, 2 nodes/wave (32 lanes/node, 8 dims/lane), packed
// cvt + f32x2 math, chunk-of-4 double-buffered prefetch with COMPILE-TIME
// constant buffer indices (full unroll) so all k/v buffers stay in VGPRs.
// ---------------------------------------------------------------------------
__device__ __forceinline__ int attn_slot(int j, int ne, int nid, int sl,
                                         const int* __restrict__ csr, int e0) {
  return (j == ne - 1) ? nid : (j < 32 ? __shfl(sl, j, 32) : csr[e0 + j]);
}

__device__ __forceinline__ void attn_load4(const unsigned char* __restrict__ qkv8,
                                           int c0, int ne, int nid, int sl,
                                           const int* __restrict__ csr, int e0, int l32,
                                           uint2 (&bk)[4], uint2 (&bv)[4]) {
#pragma unroll
  for (int t = 0; t < 4; ++t) {
    int j = c0 + t;
    if (j < ne) {
      int s = attn_slot(j, ne, nid, sl, csr, e0);
      const unsigned char* row = qkv8 + ((size_t)(s * 3) << 8) + l32 * 8;
      bk[t] = *(const uint2*)(row + 256);
      bv[t] = *(const uint2*)(row + 512);
    }
  }
}

__device__ __forceinline__ void attn_proc4(int c0, int ne,
                                           const f32x2& q01, const f32x2& q23,
                                           const f32x2& q45, const f32x2& q67,
                                           const uint2 (&bk)[4], const uint2 (&bv)[4],
                                           f32x2& a01, f32x2& a23, f32x2& a45, f32x2& a67,
                                           float& l) {
  const float C = 0.25503398f;  // (1/sqrt(32)) * log2(e)
#pragma unroll
  for (int t = 0; t < 4; ++t) {
    int j = c0 + t;
    if (j < ne) {
      uint2 kr = bk[t], vr = bv[t];
      f32x2 d = q01 * __builtin_amdgcn_cvt_pk_f32_fp8(kr.x, 0);
      d += q23 * __builtin_amdgcn_cvt_pk_f32_fp8(kr.x, 1);
      d += q45 * __builtin_amdgcn_cvt_pk_f32_fp8(kr.y, 0);
      d += q67 * __builtin_amdgcn_cvt_pk_f32_fp8(kr.y, 1);
      float p = d[0] + d[1];
      p += __shfl_xor(p, 1);
      p += __shfl_xor(p, 2);
      float ev = __builtin_amdgcn_exp2f(fminf(p * C, 86.f));
      f32x2 ev2 = {ev, ev};
      a01 += ev2 * __builtin_amdgcn_cvt_pk_f32_fp8(vr.x, 0);
      a23 += ev2 * __builtin_amdgcn_cvt_pk_f32_fp8(vr.x, 1);
      a45 += ev2 * __builtin_amdgcn_cvt_pk_f32_fp8(vr.y, 0);
      a67 += ev2 * __builtin_amdgcn_cvt_pk_f32_fp8(vr.y, 1);
      l += ev;
    }
  }
}

__global__ __launch_bounds__(256) void attn_k(const unsigned char* __restrict__ qkv8,
                                              const int* __restrict__ off,
                                              const int* __restrict__ csr,
                                              const int* __restrict__ deg,
                                              bf16_t* __restrict__ agg) {
  const int sub = threadIdx.x >> 5;              // 0..7 within block
  const int nid = blockIdx.x * 8 + sub;
  const int l32 = threadIdx.x & 31;              // lane within node group

  const unsigned char* nb = qkv8 + (size_t)((nid * 3) << 8);
  uint2 qw = *(const uint2*)(nb + l32 * 8);
  f32x2 q01 = __builtin_amdgcn_cvt_pk_f32_fp8(qw.x, 0);
  f32x2 q23 = __builtin_amdgcn_cvt_pk_f32_fp8(qw.x, 1);
  f32x2 q45 = __builtin_amdgcn_cvt_pk_f32_fp8(qw.y, 0);
  f32x2 q67 = __builtin_amdgcn_cvt_pk_f32_fp8(qw.y, 1);

  const int e0 = off[nid], e1 = off[nid + 1];
  const int ne = e1 - e0 + 1;                    // + self edge (last)
  int sl = (l32 < ne - 1) ? csr[e0 + l32] : nid; // neighbor list in regs (32 slots)

  uint2 kA[4], vA[4], kB[4], vB[4];
  float l = 0.f;
  f32x2 a01 = {0.f, 0.f}, a23 = {0.f, 0.f}, a45 = {0.f, 0.f}, a67 = {0.f, 0.f};

  attn_load4(qkv8, 0, ne, nid, sl, csr, e0, l32, kA, vA);
  for (int c = 0; c < ne; c += 8) {
    attn_load4(qkv8, c + 4, ne, nid, sl, csr, e0, l32, kB, vB);
    attn_proc4(c, ne, q01, q23, q45, q67, kA, vA, a01, a23, a45, a67, l);
    attn_load4(qkv8, c + 8, ne, nid, sl, csr, e0, l32, kA, vA);
    attn_proc4(c + 4, ne, q01, q23, q45, q67, kB, vB, a01, a23, a45, a67, l);
  }

  float inv = (deg[nid] > 0) ? 1.f / l : 0.f;
  bf16x8 ov;
  ov[0] = (bf16_t)(a01[0] * inv); ov[1] = (bf16_t)(a01[1] * inv);
  ov[2] = (bf16_t)(a23[0] * inv); ov[3] = (bf16_t)(a23[1] * inv);
  ov[4] = (bf16_t)(a45[0] * inv); ov[5] = (bf16_t)(a45[1] * inv);
  ov[6] = (bf16_t)(a67[0] * inv); ov[7] = (bf16_t)(a67[1] * inv);
  *(bf16x8*)(agg + (size_t)nid * 256 + l32 * 8) = ov;
}

// ---------------------------------------------------------------------------
// MFMA GEMM (128x128 tile, BK=64, global_load_lds + XOR swizzle).
// MODE 0: bf16 store; 1: gelu->bf16; 4: out2 = h + val (final); 7: fp8 store.
// (a) XCD-bijective block swizzle; (b) LDS-staged coalesced epilogue.
// ---------------------------------------------------------------------------
template <int MODE, bool FUSED3>
__global__ __launch_bounds__(256) void gemm_kernel(const bf16_t* __restrict__ A,
                                                   const bf16_t* __restrict__ BT,
                                                   const void* b0, const void* b1, const void* b2,
                                                   long boff,
                                                   const int* f0, const int* f1, const int* f2,
                                                   void* __restrict__ Cout,
                                                   float* __restrict__ out2,
                                                   int N, int K) {
  const int fl0 = *f0;
  const int fl1 = FUSED3 ? *f1 : 0;
  const int fl2 = FUSED3 ? *f2 : 0;

  // XCD-bijective swizzle: gridDim.y (=256) is a multiple of 8. Each XCD owns
  // a contiguous band of gridDim.y/8 A-panels and sweeps all gridDim.x blocks
  // of a panel consecutively (x fastest) -> panel is L2-resident per XCD.
  const int gx = gridDim.x;
  const int ybnd = gridDim.y >> 3;               // panels per XCD band
  int b = blockIdx.y * gx + blockIdx.x;
  int xcd = b & 7;
  int j0 = b >> 3;
  int yloc = j0 / gx;
  int xloc = j0 - yloc * gx;
  const int bm = (xcd * ybnd + yloc) * 128;
  const int bn = xloc * 128;

  const int tid = threadIdx.x;
  const int lane = tid & 63;
  const int wid = tid >> 6;
  const int wr = wid >> 1, wc = wid & 1;
  const int lrow = lane & 15;
  const int lquad = lane >> 4;
  const int l8 = lane >> 3;
  const int u = lane & 7;

  __shared__ __align__(16) char smem[32768];
  bf16_t* As = (bf16_t*)smem;                    // 16 KB
  bf16_t* Bs = (bf16_t*)(smem + 16384);          // 16 KB

  const bf16_t* aptr[4];
  const bf16_t* bptr[4];
#pragma unroll
  for (int c = 0; c < 4; ++c) {
    int row = (wid * 4 + c) * 8 + l8;
    int kseg = (u ^ l8) << 3;
    aptr[c] = A + (size_t)(bm + row) * K + kseg;
    bptr[c] = BT + (size_t)(bn + row) * K + kseg;
  }

  f32x4 acc[4][4];
#pragma unroll
  for (int i = 0; i < 4; i++)
#pragma unroll
    for (int j = 0; j < 4; j++)
#pragma unroll
      for (int r = 0; r < 4; r++) acc[i][j][r] = 0.f;

  for (int k0 = 0; k0 < K; k0 += 64) {
#pragma unroll
    for (int c = 0; c < 4; ++c) {
      int chunk = wid * 4 + c;
      __builtin_amdgcn_global_load_lds(GLB_PTR(aptr[c] + k0), LDS_PTR(As + chunk * 512), 16, 0, 0);
      __builtin_amdgcn_global_load_lds(GLB_PTR(bptr[c] + k0), LDS_PTR(Bs + chunk * 512), 16, 0, 0);
    }
    __syncthreads();
#pragma unroll
    for (int ks = 0; ks < 2; ++ks) {
      bf16x8 a[4], b2v[4];
#pragma unroll
      for (int i = 0; i < 4; i++) {
        int pu = ((ks * 4 + lquad) ^ (lrow & 7)) * 8;
        a[i] = *(const bf16x8*)(&As[(wr * 64 + i * 16 + lrow) * 64 + pu]);
        b2v[i] = *(const bf16x8*)(&Bs[(wc * 64 + i * 16 + lrow) * 64 + pu]);
      }
#pragma unroll
      for (int i = 0; i < 4; i++)
#pragma unroll
        for (int j = 0; j < 4; j++)
          acc[i][j] = __builtin_amdgcn_mfma_f32_16x16x32_bf16(a[i], b2v[j], acc[i][j], 0, 0, 0);
    }
    __syncthreads();
  }

  // Epilogue. C/D layout: col = lane&15, row = (lane>>4)*4 + reg.
  if (MODE == 4) {
    // fp32 path: 64B row segments are full sectors; store directly.
#pragma unroll
    for (int j = 0; j < 4; j++) {
      int n = bn + wc * 64 + j * 16 + lrow;
      float bv = load_ext(b0, boff + n, fl0);
#pragma unroll
      for (int i = 0; i < 4; i++) {
        int m0 = bm + wr * 64 + i * 16 + lquad * 4;
#pragma unroll
        for (int r = 0; r < 4; r++) {
          float val = acc[i][j][r] + bv;
          size_t idx = (size_t)(m0 + r) * N + n;
          out2[idx] = ((const float*)Cout)[idx] + val;
        }
      }
    }
  } else {
    // bf16/fp8 paths: stage 128x128 tile in LDS, then coalesced dwordx4 out.
#pragma unroll
    for (int j = 0; j < 4; j++) {
      int n = bn + wc * 64 + j * 16 + lrow;
      float bv;
      if (FUSED3) {
        int seg = n >> 8;
        const void* bp = (seg == 0) ? b0 : ((seg == 1) ? b1 : b2);
        int fl = (seg == 0) ? fl0 : ((seg == 1) ? fl1 : fl2);
        bv = load_ext(bp, boff + (n & 255), fl);
      } else {
        bv = load_ext(b0, boff + n, fl0);
      }
      int ncol = wc * 64 + j * 16 + lrow;
#pragma unroll
      for (int i = 0; i < 4; i++) {
        int m0 = wr * 64 + i * 16 + lquad * 4;
#pragma unroll
        for (int r = 0; r < 4; r++) {
          float val = acc[i][j][r] + bv;
          if (MODE == 0) {
            ((bf16_t*)smem)[(m0 + r) * 128 + ncol] = (bf16_t)val;
          } else if (MODE == 1) {
            float gl = 0.5f * val * (1.f + erff(val * 0.7071067811865475f));
            ((bf16_t*)smem)[(m0 + r) * 128 + ncol] = (bf16_t)gl;
          } else if (MODE == 7) {
            unsigned pk = __builtin_amdgcn_cvt_pk_fp8_f32(val, val, 0u, false);
            ((unsigned char*)smem)[(m0 + r) * 128 + ncol] = (unsigned char)(pk & 0xFF);
          }
        }
      }
    }
    __syncthreads();
    if (MODE == 7) {
      // 128x128 fp8 tile = 16 KB; per row 128 B = 8 lanes x 16 B.
      const unsigned char* ts = (const unsigned char*)smem;
#pragma unroll
      for (int p = 0; p < 4; ++p) {
        int row = p * 32 + (tid >> 3);
        int col = (tid & 7) * 16;
        *(int4*)((unsigned char*)Cout + (size_t)(bm + row) * N + bn + col) =
            *(const int4*)(ts + row * 128 + col);
      }
    } else {
      // 128x128 bf16 tile = 32 KB; per row 256 B = 16 lanes x 16 B.
      const bf16_t* ts = (const bf16_t*)smem;
#pragma unroll
      for (int p = 0; p < 8; ++p) {
        int row = p * 16 + (tid >> 4);
        int col = (tid & 15) * 8;
        *(int4*)((bf16_t*)Cout + (size_t)(bm + row) * N + bn + col) =
            *(const int4*)(ts + row * 128 + col);
      }
    }
  }
}

// ---------------------------------------------------------------------------
// GEMM + fused LayerNorm, v4: NO LDS staging at all. 16 rows x 256 cols per
// 256-thread block; MFMA operands loaded straight from global (A: 16 rows x
// 64B segments, coalesced; B: L2-resident). No k-loop barriers, no vmcnt(0)
// drains, no bank conflicts (v3's BK=32 LDS layout was a structural 4-way
// conflict; v2's BK=64 was barrier/occupancy-bound at 2 TB/s). LDS = LN
// stats only (~0.8 KB) -> occupancy is VGPR-bound, loads pipeline freely.
// Writes h (fp32, += residual if RES) and xn = LN(h_new) (bf16).
// ---------------------------------------------------------------------------
template <bool RES>
__global__ __launch_bounds__(256) void gemm_ln(const bf16_t* __restrict__ A,
                                               const bf16_t* __restrict__ BT,
                                               const void* bias, long boff, const int* bfp,
                                               const void* g, long goff, const int* gfp,
                                               const void* bv2, long bvoff, const int* bvfp,
                                               float* __restrict__ h,
                                               bf16_t* __restrict__ xn,
                                               int K) {
  const int flb = *bfp, flg = *gfp, flbv = *bvfp;
  const int bm = blockIdx.y * 16;
  const int tid = threadIdx.x;
  const int lane = tid & 63;
  const int wid = tid >> 6;
  const int lrow = lane & 15;
  const int lquad = lane >> 4;

  __shared__ float sums[16][4], sqs[16][4];
  __shared__ float mus[16], rss[16];

  // Direct global fragment pointers (identical operand values to the staged
  // version): a = A[bm+lrow][k0 + lquad*8], b = BT[col][k0 + lquad*8].
  const bf16_t* arow = A + (size_t)(bm + lrow) * K + lquad * 8;
  const bf16_t* brow[4];
#pragma unroll
  for (int j = 0; j < 4; ++j)
    brow[j] = BT + (size_t)(wid * 64 + j * 16 + lrow) * K + lquad * 8;

  f32x4 acc[4];
#pragma unroll
  for (int j = 0; j < 4; j++)
#pragma unroll
    for (int r = 0; r < 4; r++) acc[j][r] = 0.f;

#pragma unroll 4
  for (int k0 = 0; k0 < K; k0 += 32) {
    bf16x8 a = *(const bf16x8*)(arow + k0);
#pragma unroll
    for (int j = 0; j < 4; j++) {
      bf16x8 b = *(const bf16x8*)(brow[j] + k0);
      acc[j] = __builtin_amdgcn_mfma_f32_16x16x32_bf16(a, b, acc[j], 0, 0, 0);
    }
  }

  // epilogue: val = acc + bias (+ h_old); store h_new; row stats; LN -> xn
#pragma unroll
  for (int j = 0; j < 4; j++) {
    int n = wid * 64 + j * 16 + lrow;
    float bvv = load_ext(bias, boff + n, flb);
#pragma unroll
    for (int r = 0; r < 4; r++) {
      float v = acc[j][r] + bvv;
      size_t idx = (size_t)(bm + lquad * 4 + r) * 256 + n;
      if (RES) v += h[idx];
      acc[j][r] = v;
      h[idx] = v;
    }
  }
  // per-row partial sums over this wave's 64 cols
#pragma unroll
  for (int r = 0; r < 4; r++) {
    float s = acc[0][r] + acc[1][r] + acc[2][r] + acc[3][r];
    float q = acc[0][r] * acc[0][r] + acc[1][r] * acc[1][r]
            + acc[2][r] * acc[2][r] + acc[3][r] * acc[3][r];
#pragma unroll
    for (int o = 1; o <= 8; o <<= 1) {
      s += __shfl_xor(s, o);
      q += __shfl_xor(q, o);
    }
    if (lrow == 0) {
      int row = lquad * 4 + r;
      sums[row][wid] = s;
      sqs[row][wid] = q;
    }
  }
  __syncthreads();
  if (tid < 16) {
    float s = sums[tid][0] + sums[tid][1] + sums[tid][2] + sums[tid][3];
    float q = sqs[tid][0] + sqs[tid][1] + sqs[tid][2] + sqs[tid][3];
    float mu = s * (1.f / 256.f);
    float var = q * (1.f / 256.f) - mu * mu;
    mus[tid] = mu;
    rss[tid] = rsqrtf(var + 1e-5f);
  }
  __syncthreads();
#pragma unroll
  for (int j = 0; j < 4; j++) {
    int n = wid * 64 + j * 16 + lrow;
    float gv = load_ext(g, goff + n, flg);
    float bb = load_ext(bv2, bvoff + n, flbv);
#pragma unroll
    for (int r = 0; r < 4; r++) {
      int row = lquad * 4 + r;
      float xv = (acc[j][r] - mus[row]) * rss[row] * gv + bb;
      xn[(size_t)(bm + row) * 256 + n] = (bf16_t)xv;
    }
  }
}

// ---------------------------------------------------------------------------
extern "C" void kernel_launch(void* const* d_in, const int* in_sizes, int n_in,
                              void* d_out, int out_size, void* d_ws, size_t ws_size,
                              hipStream_t stream) {
  const void* ei = d_in[1];

  char* ws = (char*)d_ws;
  size_t o = 0;
  int* flags  = (int*)(ws + o);    o += 256;
  int* deg    = (int*)(ws + o);    o += (size_t)N_NODES * 4;
  int* cursor = (int*)(ws + o);    o += (size_t)N_NODES * 4;
  int* off    = (int*)(ws + o);    o += 131328;
  int* csr    = (int*)(ws + o);    o += (size_t)N_EDGES * 4;
  bf16_t* wT  = (bf16_t*)(ws + o); o += (size_t)1638400 * 2;
  float* h    = (float*)(ws + o);  o += (size_t)N_NODES * 256 * 4;   // 32 MB
  bf16_t* xn  = (bf16_t*)(ws + o); o += (size_t)N_NODES * 256 * 2;   // 16 MB
  bf16_t* big = (bf16_t*)(ws + o); o += (size_t)N_NODES * 1024 * 2;  // 64 MB arena
  bf16_t* xb = big;                          // converted x (dead before QKV)
  unsigned char* qkv8 = (unsigned char*)big; // [N,768] fp8 q|k|v
  bf16_t* ab = xn;                           // agg aliases xn (row-exclusive in gemm_ln)
  bf16_t* ffnb = big;                        // [N,1024] bf16 (qkv8 dead then)

  hipMemsetAsync(deg, 0, N_NODES * 4, stream);
  hipMemsetAsync(cursor, 0, N_NODES * 4, stream);

  SniffArgs sa;
  for (int b = 0; b < 20; ++b) {
    sa.ptr[b] = d_in[b];
    sa.elems[b] = in_sizes[b];
    sa.kind[b] = (b == 1) ? 1 : 0;
  }
  sniff_all<<<20, 256, 0, stream>>>(sa, flags);

  convert_x<<<(N_NODES * 256) / 1024, 256, 0, stream>>>(d_in[0], xb, flags + 0);

  TransArgs ta;
  ta.flags = flags;
  int tiles = 0, idx = 0;
  auto add = [&](int slot, long soff, bf16_t* dst, int K, int N) {
    ta.d[idx].src = d_in[slot]; ta.d[idx].soff = soff; ta.d[idx].dst = dst;
    ta.d[idx].K = K; ta.d[idx].N = N; ta.d[idx].tile0 = tiles; ta.d[idx].fidx = slot;
    tiles += (K / 32) * (N / 32);
    ++idx;
  };
  bf16_t* wTin = wT;
  auto layer_base = [&](int l) { return wT + 65536 + (size_t)l * 786432; };
  add(2, 0, wTin, 256, 256);  // w_in
  for (int l = 0; l < 2; ++l) {
    bf16_t* base = layer_base(l);
    add(8,  (long)l * 65536,  base + 0,      256, 256);   // wq^T
    add(10, (long)l * 65536,  base + 65536,  256, 256);   // wk^T
    add(12, (long)l * 65536,  base + 131072, 256, 256);   // wv^T
    add(14, (long)l * 65536,  base + 196608, 256, 256);   // wo^T
    add(16, (long)l * 262144, base + 262144, 256, 1024);  // w1^T
    add(18, (long)l * 262144, base + 524288, 1024, 256);  // w2^T
  }
  transpose_many<<<tiles, 256, 0, stream>>>(ta);

  deg_count<<<N_EDGES / 256, 256, 0, stream>>>(ei, flags + 1, deg);
  scan_offsets<<<1, 1024, 0, stream>>>(deg, off);
  scatter_edges<<<N_EDGES / 256, 256, 0, stream>>>(ei, flags + 1, off, cursor, csr);

  // input proj + LN1(l0): h = x@w_in + b_in; xn = LN(h)
  gemm_ln<false><<<dim3(1, 2048), 256, 0, stream>>>(
      xb, wTin, d_in[3], 0, flags + 3,
      d_in[4], 0, flags + 4, d_in[5], 0, flags + 5, h, xn, 256);

  for (int l = 0; l < 2; ++l) {
    bf16_t* base = layer_base(l);
    // fused QKV -> fp8 [N,768]
    gemm_kernel<7, true><<<dim3(6, 256), 256, 0, stream>>>(
        xn, base, d_in[9], d_in[11], d_in[13], (long)l * 256,
        flags + 9, flags + 11, flags + 13, qkv8, nullptr, 768, 256);
    attn_k<<<N_NODES / 8, 256, 0, stream>>>(qkv8, off, csr, deg, ab);
    // o_proj + residual + LN2(l): h += ab@wo + bo; xn = LN(h)
    gemm_ln<true><<<dim3(1, 2048), 256, 0, stream>>>(
        ab, base + 196608, d_in[15], (long)l * 256, flags + 15,
        d_in[6], (long)l * 256, flags + 6, d_in[7], (long)l * 256, flags + 7,
        h, xn, 256);
    // FFN1: gelu -> bf16 [N,1024]
    gemm_kernel<1, false><<<dim3(8, 256), 256, 0, stream>>>(
        xn, base + 262144, d_in[17], nullptr, nullptr, (long)l * 1024,
        flags + 17, flags + 17, flags + 17, ffnb, nullptr, 1024, 256);
    if (l == 0) {
      // FFN2 + residual + LN1(l1): h += ffn; xn = LN(h)
      gemm_ln<true><<<dim3(1, 2048), 256, 0, stream>>>(
          ffnb, base + 524288, d_in[19], 0, flags + 19,
          d_in[4], 256, flags + 4, d_in[5], 256, flags + 5, h, xn, 1024);
    } else {
      // final: d_out = h + ffn
      gemm_kernel<4, false><<<dim3(2, 256), 256, 0, stream>>>(
          ffnb, base + 524288, d_in[19], nullptr, nullptr, (long)l * 256,
          flags + 19, flags + 19, flags + 19, h, (float*)d_out, 256, 1024);
    }
  }
}

// Round 7
// 567.972 us; speedup vs baseline: 1.3604x; 1.3604x over previous
//
#include <hip/hip_runtime.h>
#include <hip/hip_bf16.h>
#include <math.h>

typedef __bf16 bf16_t;
typedef __bf16 bf16x4 __attribute__((ext_vector_type(4)));
typedef __bf16 bf16x8 __attribute__((ext_vector_type(8)));
typedef float f32x4 __attribute__((ext_vector_type(4)));
typedef float f32x2 __attribute__((ext_vector_type(2)));

static constexpr int N_NODES = 32768;
static constexpr int N_EDGES = N_NODES * 16;

#define GLB_PTR(p) ((const __attribute__((address_space(1))) void*)(p))
#define LDS_PTR(p) ((__attribute__((address_space(3))) void*)(p))

// flag per tensor: 0 = fp32, 1 = bf16, 2 = all-zero (return 0 without reading)
__device__ __forceinline__ float load_ext(const void* p, long i, int fl) {
  if (fl == 2) return 0.f;
  return fl ? (float)((const bf16_t*)p)[i] : ((const float*)p)[i];
}

// ---------------------------------------------------------------------------
// Per-tensor dtype sniffer. kind 0 = float tensor, kind 1 = int tensor.
// ---------------------------------------------------------------------------
struct SniffArgs {
  const void* ptr[20];
  int elems[20];
  int kind[20];
};

__global__ __launch_bounds__(256) void sniff_all(SniffArgs a, int* flags) {
  int b = blockIdx.x;
  int t = threadIdx.x;
  __shared__ int s1[256], s2[256];
  if (a.kind[b] == 0) {
    const unsigned short* p = (const unsigned short*)a.ptr[b];
    int pairs = min(1024, a.elems[b] / 2);
    int sane = 0, nz = 0;
    for (int i = t; i < pairs; i += 256) {
      unsigned short we = p[2 * i], wo = p[2 * i + 1];
      if (we | wo) nz++;
      int e = (we >> 7) & 0xFF;
      if (we != 0 && e >= 100 && e <= 140) sane++;
    }
    s1[t] = sane; s2[t] = nz;
    __syncthreads();
    for (int o = 128; o >= 1; o >>= 1) {
      if (t < o) { s1[t] += s1[t + o]; s2[t] += s2[t + o]; }
      __syncthreads();
    }
    if (t == 0)
      flags[b] = (s2[0] == 0) ? 2 : ((2 * s1[0] > pairs) ? 1 : 0);
  } else {
    const int* ip = (const int*)a.ptr[b];
    int n = min(512, a.elems[b] / 2);
    int zeros = 0;
    for (int i = t; i < n; i += 256)
      if (ip[2 * i + 1] == 0) zeros++;
    s1[t] = zeros;
    __syncthreads();
    for (int o = 128; o >= 1; o >>= 1) {
      if (t < o) s1[t] += s1[t + o];
      __syncthreads();
    }
    if (t == 0) flags[b] = (s1[0] * 4 > n * 3) ? 1 : 0;
  }
}

__global__ __launch_bounds__(256) void convert_x(const void* src, bf16_t* dst,
                                                 const int* flagp) {
  int fl = *flagp;
  int i = (blockIdx.x * 256 + threadIdx.x) * 4;
  if (fl == 1) {
    *(int2*)(dst + i) = *(const int2*)((const bf16_t*)src + i);
  } else if (fl == 0) {
    float4 v = *(const float4*)((const float*)src + i);
    dst[i] = (bf16_t)v.x; dst[i + 1] = (bf16_t)v.y;
    dst[i + 2] = (bf16_t)v.z; dst[i + 3] = (bf16_t)v.w;
  } else {
    dst[i] = (bf16_t)0.f; dst[i + 1] = (bf16_t)0.f;
    dst[i + 2] = (bf16_t)0.f; dst[i + 3] = (bf16_t)0.f;
  }
}

// ---------------------------------------------------------------------------
// Batched 32x32 tile transpose: dst[n*K+k] = src[k*N+n], per-desc dtype flag.
// ---------------------------------------------------------------------------
struct TransDesc { const void* src; long soff; bf16_t* dst; int K; int N; int tile0; int fidx; };
struct TransArgs { TransDesc d[13]; const int* flags; };

__global__ __launch_bounds__(256) void transpose_many(TransArgs args) {
  __shared__ bf16_t tile[32][33];
  int blk = blockIdx.x;
  int i = 0;
#pragma unroll
  for (int j = 1; j < 13; ++j)
    if (blk >= args.d[j].tile0) i = j;
  TransDesc dd = args.d[i];
  int fl = args.flags[dd.fidx];
  int t = blk - dd.tile0;
  int tiles_x = dd.N / 32;
  int nbase = (t % tiles_x) * 32;
  int kbase = (t / tiles_x) * 32;
  int tx = threadIdx.x & 31, ty = threadIdx.x >> 5;
#pragma unroll
  for (int j = 0; j < 32; j += 8)
    tile[ty + j][tx] = (bf16_t)load_ext(dd.src, dd.soff + (long)(kbase + ty + j) * dd.N + nbase + tx, fl);
  __syncthreads();
#pragma unroll
  for (int j = 0; j < 32; j += 8)
    dd.dst[(size_t)(nbase + ty + j) * dd.K + kbase + tx] = tile[tx][ty + j];
}

// ---------------------------------------------------------------------------
// CSR build (edge_index int32 or int64 per flags[1])
// ---------------------------------------------------------------------------
__device__ __forceinline__ int edge_at(const void* ei, long i, int fl64) {
  return fl64 ? (int)((const long long*)ei)[i] : ((const int*)ei)[i];
}

__global__ __launch_bounds__(256) void deg_count(const void* __restrict__ ei,
                                                 const int* flagp,
                                                 int* __restrict__ deg) {
  int fl = *flagp;
  int e = blockIdx.x * 256 + threadIdx.x;
  if (e < N_EDGES) atomicAdd(&deg[edge_at(ei, (long)N_EDGES + e, fl)], 1);
}

__global__ __launch_bounds__(1024) void scan_offsets(const int* __restrict__ deg,
                                                     int* __restrict__ off) {
  __shared__ int s[1024];
  int t = threadIdx.x;
  int base = t * 32;
  int sum = 0;
  for (int i = 0; i < 32; ++i) sum += deg[base + i];
  s[t] = sum;
  __syncthreads();
  for (int o = 1; o < 1024; o <<= 1) {
    int v = (t >= o) ? s[t - o] : 0;
    __syncthreads();
    s[t] += v;
    __syncthreads();
  }
  int run = s[t] - sum;
  for (int i = 0; i < 32; ++i) { off[base + i] = run; run += deg[base + i]; }
  if (t == 1023) off[N_NODES] = run;
}

__global__ __launch_bounds__(256) void scatter_edges(const void* __restrict__ ei,
                                                     const int* flagp,
                                                     const int* __restrict__ off,
                                                     int* __restrict__ cursor,
                                                     int* __restrict__ csr) {
  int fl = *flagp;
  int e = blockIdx.x * 256 + threadIdx.x;
  if (e < N_EDGES) {
    int d = edge_at(ei, (long)N_EDGES + e, fl);
    int p = off[d] + atomicAdd(&cursor[d], 1);
    csr[p] = edge_at(ei, e, fl);
  }
}

// ---------------------------------------------------------------------------
// Attention v6: fp8 q/k/v, 2 nodes/wave (32 lanes/node, 8 dims/lane), packed
// cvt + f32x2 math, chunk-of-4 double-buffered prefetch with COMPILE-TIME
// constant buffer indices (full unroll) so all k/v buffers stay in VGPRs.
// ---------------------------------------------------------------------------
__device__ __forceinline__ int attn_slot(int j, int ne, int nid, int sl,
                                         const int* __restrict__ csr, int e0) {
  return (j == ne - 1) ? nid : (j < 32 ? __shfl(sl, j, 32) : csr[e0 + j]);
}

__device__ __forceinline__ void attn_load4(const unsigned char* __restrict__ qkv8,
                                           int c0, int ne, int nid, int sl,
                                           const int* __restrict__ csr, int e0, int l32,
                                           uint2 (&bk)[4], uint2 (&bv)[4]) {
#pragma unroll
  for (int t = 0; t < 4; ++t) {
    int j = c0 + t;
    if (j < ne) {
      int s = attn_slot(j, ne, nid, sl, csr, e0);
      const unsigned char* row = qkv8 + ((size_t)(s * 3) << 8) + l32 * 8;
      bk[t] = *(const uint2*)(row + 256);
      bv[t] = *(const uint2*)(row + 512);
    }
  }
}

__device__ __forceinline__ void attn_proc4(int c0, int ne,
                                           const f32x2& q01, const f32x2& q23,
                                           const f32x2& q45, const f32x2& q67,
                                           const uint2 (&bk)[4], const uint2 (&bv)[4],
                                           f32x2& a01, f32x2& a23, f32x2& a45, f32x2& a67,
                                           float& l) {
  const float C = 0.25503398f;  // (1/sqrt(32)) * log2(e)
#pragma unroll
  for (int t = 0; t < 4; ++t) {
    int j = c0 + t;
    if (j < ne) {
      uint2 kr = bk[t], vr = bv[t];
      f32x2 d = q01 * __builtin_amdgcn_cvt_pk_f32_fp8(kr.x, 0);
      d += q23 * __builtin_amdgcn_cvt_pk_f32_fp8(kr.x, 1);
      d += q45 * __builtin_amdgcn_cvt_pk_f32_fp8(kr.y, 0);
      d += q67 * __builtin_amdgcn_cvt_pk_f32_fp8(kr.y, 1);
      float p = d[0] + d[1];
      p += __shfl_xor(p, 1);
      p += __shfl_xor(p, 2);
      float ev = __builtin_amdgcn_exp2f(fminf(p * C, 86.f));
      f32x2 ev2 = {ev, ev};
      a01 += ev2 * __builtin_amdgcn_cvt_pk_f32_fp8(vr.x, 0);
      a23 += ev2 * __builtin_amdgcn_cvt_pk_f32_fp8(vr.x, 1);
      a45 += ev2 * __builtin_amdgcn_cvt_pk_f32_fp8(vr.y, 0);
      a67 += ev2 * __builtin_amdgcn_cvt_pk_f32_fp8(vr.y, 1);
      l += ev;
    }
  }
}

__global__ __launch_bounds__(256) void attn_k(const unsigned char* __restrict__ qkv8,
                                              const int* __restrict__ off,
                                              const int* __restrict__ csr,
                                              const int* __restrict__ deg,
                                              bf16_t* __restrict__ agg) {
  const int sub = threadIdx.x >> 5;              // 0..7 within block
  const int nid = blockIdx.x * 8 + sub;
  const int l32 = threadIdx.x & 31;              // lane within node group

  const unsigned char* nb = qkv8 + (size_t)((nid * 3) << 8);
  uint2 qw = *(const uint2*)(nb + l32 * 8);
  f32x2 q01 = __builtin_amdgcn_cvt_pk_f32_fp8(qw.x, 0);
  f32x2 q23 = __builtin_amdgcn_cvt_pk_f32_fp8(qw.x, 1);
  f32x2 q45 = __builtin_amdgcn_cvt_pk_f32_fp8(qw.y, 0);
  f32x2 q67 = __builtin_amdgcn_cvt_pk_f32_fp8(qw.y, 1);

  const int e0 = off[nid], e1 = off[nid + 1];
  const int ne = e1 - e0 + 1;                    // + self edge (last)
  int sl = (l32 < ne - 1) ? csr[e0 + l32] : nid; // neighbor list in regs (32 slots)

  uint2 kA[4], vA[4], kB[4], vB[4];
  float l = 0.f;
  f32x2 a01 = {0.f, 0.f}, a23 = {0.f, 0.f}, a45 = {0.f, 0.f}, a67 = {0.f, 0.f};

  attn_load4(qkv8, 0, ne, nid, sl, csr, e0, l32, kA, vA);
  for (int c = 0; c < ne; c += 8) {
    attn_load4(qkv8, c + 4, ne, nid, sl, csr, e0, l32, kB, vB);
    attn_proc4(c, ne, q01, q23, q45, q67, kA, vA, a01, a23, a45, a67, l);
    attn_load4(qkv8, c + 8, ne, nid, sl, csr, e0, l32, kA, vA);
    attn_proc4(c + 4, ne, q01, q23, q45, q67, kB, vB, a01, a23, a45, a67, l);
  }

  float inv = (deg[nid] > 0) ? 1.f / l : 0.f;
  bf16x8 ov;
  ov[0] = (bf16_t)(a01[0] * inv); ov[1] = (bf16_t)(a01[1] * inv);
  ov[2] = (bf16_t)(a23[0] * inv); ov[3] = (bf16_t)(a23[1] * inv);
  ov[4] = (bf16_t)(a45[0] * inv); ov[5] = (bf16_t)(a45[1] * inv);
  ov[6] = (bf16_t)(a67[0] * inv); ov[7] = (bf16_t)(a67[1] * inv);
  *(bf16x8*)(agg + (size_t)nid * 256 + l32 * 8) = ov;
}

// ---------------------------------------------------------------------------
// MFMA GEMM (128x128 tile, BK=64, global_load_lds + XOR swizzle).
// MODE 0: bf16 store; 1: gelu->bf16; 4: out2 = h + val (final); 7: fp8 store.
// (a) XCD-bijective block swizzle; (b) LDS-staged coalesced epilogue.
// ---------------------------------------------------------------------------
template <int MODE, bool FUSED3>
__global__ __launch_bounds__(256) void gemm_kernel(const bf16_t* __restrict__ A,
                                                   const bf16_t* __restrict__ BT,
                                                   const void* b0, const void* b1, const void* b2,
                                                   long boff,
                                                   const int* f0, const int* f1, const int* f2,
                                                   void* __restrict__ Cout,
                                                   float* __restrict__ out2,
                                                   int N, int K) {
  const int fl0 = *f0;
  const int fl1 = FUSED3 ? *f1 : 0;
  const int fl2 = FUSED3 ? *f2 : 0;

  // XCD-bijective swizzle: gridDim.y (=256) is a multiple of 8. Each XCD owns
  // a contiguous band of gridDim.y/8 A-panels and sweeps all gridDim.x blocks
  // of a panel consecutively (x fastest) -> panel is L2-resident per XCD.
  const int gx = gridDim.x;
  const int ybnd = gridDim.y >> 3;               // panels per XCD band
  int b = blockIdx.y * gx + blockIdx.x;
  int xcd = b & 7;
  int j0 = b >> 3;
  int yloc = j0 / gx;
  int xloc = j0 - yloc * gx;
  const int bm = (xcd * ybnd + yloc) * 128;
  const int bn = xloc * 128;

  const int tid = threadIdx.x;
  const int lane = tid & 63;
  const int wid = tid >> 6;
  const int wr = wid >> 1, wc = wid & 1;
  const int lrow = lane & 15;
  const int lquad = lane >> 4;
  const int l8 = lane >> 3;
  const int u = lane & 7;

  __shared__ __align__(16) char smem[32768];
  bf16_t* As = (bf16_t*)smem;                    // 16 KB
  bf16_t* Bs = (bf16_t*)(smem + 16384);          // 16 KB

  const bf16_t* aptr[4];
  const bf16_t* bptr[4];
#pragma unroll
  for (int c = 0; c < 4; ++c) {
    int row = (wid * 4 + c) * 8 + l8;
    int kseg = (u ^ l8) << 3;
    aptr[c] = A + (size_t)(bm + row) * K + kseg;
    bptr[c] = BT + (size_t)(bn + row) * K + kseg;
  }

  f32x4 acc[4][4];
#pragma unroll
  for (int i = 0; i < 4; i++)
#pragma unroll
    for (int j = 0; j < 4; j++)
#pragma unroll
      for (int r = 0; r < 4; r++) acc[i][j][r] = 0.f;

  for (int k0 = 0; k0 < K; k0 += 64) {
#pragma unroll
    for (int c = 0; c < 4; ++c) {
      int chunk = wid * 4 + c;
      __builtin_amdgcn_global_load_lds(GLB_PTR(aptr[c] + k0), LDS_PTR(As + chunk * 512), 16, 0, 0);
      __builtin_amdgcn_global_load_lds(GLB_PTR(bptr[c] + k0), LDS_PTR(Bs + chunk * 512), 16, 0, 0);
    }
    __syncthreads();
#pragma unroll
    for (int ks = 0; ks < 2; ++ks) {
      bf16x8 a[4], b2v[4];
#pragma unroll
      for (int i = 0; i < 4; i++) {
        int pu = ((ks * 4 + lquad) ^ (lrow & 7)) * 8;
        a[i] = *(const bf16x8*)(&As[(wr * 64 + i * 16 + lrow) * 64 + pu]);
        b2v[i] = *(const bf16x8*)(&Bs[(wc * 64 + i * 16 + lrow) * 64 + pu]);
      }
#pragma unroll
      for (int i = 0; i < 4; i++)
#pragma unroll
        for (int j = 0; j < 4; j++)
          acc[i][j] = __builtin_amdgcn_mfma_f32_16x16x32_bf16(a[i], b2v[j], acc[i][j], 0, 0, 0);
    }
    __syncthreads();
  }

  // Epilogue. C/D layout: col = lane&15, row = (lane>>4)*4 + reg.
  if (MODE == 4) {
    // fp32 path: 64B row segments are full sectors; store directly.
#pragma unroll
    for (int j = 0; j < 4; j++) {
      int n = bn + wc * 64 + j * 16 + lrow;
      float bv = load_ext(b0, boff + n, fl0);
#pragma unroll
      for (int i = 0; i < 4; i++) {
        int m0 = bm + wr * 64 + i * 16 + lquad * 4;
#pragma unroll
        for (int r = 0; r < 4; r++) {
          float val = acc[i][j][r] + bv;
          size_t idx = (size_t)(m0 + r) * N + n;
          out2[idx] = ((const float*)Cout)[idx] + val;
        }
      }
    }
  } else {
    // bf16/fp8 paths: stage 128x128 tile in LDS, then coalesced dwordx4 out.
#pragma unroll
    for (int j = 0; j < 4; j++) {
      int n = bn + wc * 64 + j * 16 + lrow;
      float bv;
      if (FUSED3) {
        int seg = n >> 8;
        const void* bp = (seg == 0) ? b0 : ((seg == 1) ? b1 : b2);
        int fl = (seg == 0) ? fl0 : ((seg == 1) ? fl1 : fl2);
        bv = load_ext(bp, boff + (n & 255), fl);
      } else {
        bv = load_ext(b0, boff + n, fl0);
      }
      int ncol = wc * 64 + j * 16 + lrow;
#pragma unroll
      for (int i = 0; i < 4; i++) {
        int m0 = wr * 64 + i * 16 + lquad * 4;
#pragma unroll
        for (int r = 0; r < 4; r++) {
          float val = acc[i][j][r] + bv;
          if (MODE == 0) {
            ((bf16_t*)smem)[(m0 + r) * 128 + ncol] = (bf16_t)val;
          } else if (MODE == 1) {
            float gl = 0.5f * val * (1.f + erff(val * 0.7071067811865475f));
            ((bf16_t*)smem)[(m0 + r) * 128 + ncol] = (bf16_t)gl;
          } else if (MODE == 7) {
            unsigned pk = __builtin_amdgcn_cvt_pk_fp8_f32(val, val, 0u, false);
            ((unsigned char*)smem)[(m0 + r) * 128 + ncol] = (unsigned char)(pk & 0xFF);
          }
        }
      }
    }
    __syncthreads();
    if (MODE == 7) {
      // 128x128 fp8 tile = 16 KB; per row 128 B = 8 lanes x 16 B.
      const unsigned char* ts = (const unsigned char*)smem;
#pragma unroll
      for (int p = 0; p < 4; ++p) {
        int row = p * 32 + (tid >> 3);
        int col = (tid & 7) * 16;
        *(int4*)((unsigned char*)Cout + (size_t)(bm + row) * N + bn + col) =
            *(const int4*)(ts + row * 128 + col);
      }
    } else {
      // 128x128 bf16 tile = 32 KB; per row 256 B = 16 lanes x 16 B.
      const bf16_t* ts = (const bf16_t*)smem;
#pragma unroll
      for (int p = 0; p < 8; ++p) {
        int row = p * 16 + (tid >> 4);
        int col = (tid & 15) * 8;
        *(int4*)((bf16_t*)Cout + (size_t)(bm + row) * N + bn + col) =
            *(const int4*)(ts + row * 128 + col);
      }
    }
  }
}

// ---------------------------------------------------------------------------
// GEMM + fused LayerNorm (v2, measured best: 52 us). 32 rows x 256 cols per
// 256-thread block (each wave 32x64, acc[2][4]), BK=64, global_load_lds
// staging. NOTE (measured): BK=32 LDS layout -> structural 4-way bank
// conflict (94 us); no-LDS reg-direct loads -> compiler serializes at
// VGPR=36 (190 us). The BK=64 128B-row layout + global_load_lds pipelining
// are both load-bearing. Writes h (fp32, += residual if RES) and
// xn = LN(h_new) (bf16) via cross-wave LDS row stats.
// ---------------------------------------------------------------------------
template <bool RES>
__global__ __launch_bounds__(256) void gemm_ln(const bf16_t* __restrict__ A,
                                               const bf16_t* __restrict__ BT,
                                               const void* bias, long boff, const int* bfp,
                                               const void* g, long goff, const int* gfp,
                                               const void* bv2, long bvoff, const int* bvfp,
                                               float* __restrict__ h,
                                               bf16_t* __restrict__ xn,
                                               int K) {
  const int flb = *bfp, flg = *gfp, flbv = *bvfp;
  const int bm = blockIdx.y * 32;
  const int tid = threadIdx.x;
  const int lane = tid & 63;
  const int wid = tid >> 6;
  const int lrow = lane & 15;
  const int lquad = lane >> 4;
  const int l8 = lane >> 3;
  const int u = lane & 7;

  __shared__ __align__(16) bf16_t As[32 * 64];    // 4 KB
  __shared__ __align__(16) bf16_t Bs[256 * 64];   // 32 KB
  __shared__ float sums[32][4], sqs[32][4];
  __shared__ float mus[32], rss[32];

  // A stage: one 8-row chunk per wave -> exactly one 16B load per thread
  const bf16_t* aptr = A + (size_t)(bm + wid * 8 + l8) * K + ((u ^ l8) << 3);
  const bf16_t* bptr[8];
#pragma unroll
  for (int c = 0; c < 8; ++c) {
    int chunk = wid * 8 + c;
    bptr[c] = BT + (size_t)(chunk * 8 + l8) * K + ((u ^ l8) << 3);
  }

  f32x4 acc[2][4];
#pragma unroll
  for (int i = 0; i < 2; i++)
#pragma unroll
    for (int j = 0; j < 4; j++)
#pragma unroll
      for (int r = 0; r < 4; r++) acc[i][j][r] = 0.f;

  for (int k0 = 0; k0 < K; k0 += 64) {
    __builtin_amdgcn_global_load_lds(GLB_PTR(aptr + k0), LDS_PTR(As + wid * 512), 16, 0, 0);
#pragma unroll
    for (int c = 0; c < 8; ++c)
      __builtin_amdgcn_global_load_lds(GLB_PTR(bptr[c] + k0), LDS_PTR(Bs + (wid * 8 + c) * 512), 16, 0, 0);
    __syncthreads();
#pragma unroll
    for (int ks = 0; ks < 2; ++ks) {
      bf16x8 a[2], b[4];
      int pu = ((ks * 4 + lquad) ^ (lrow & 7)) * 8;
#pragma unroll
      for (int i = 0; i < 2; i++)
        a[i] = *(const bf16x8*)(&As[(i * 16 + lrow) * 64 + pu]);
#pragma unroll
      for (int j = 0; j < 4; j++)
        b[j] = *(const bf16x8*)(&Bs[(wid * 64 + j * 16 + lrow) * 64 + pu]);
#pragma unroll
      for (int i = 0; i < 2; i++)
#pragma unroll
        for (int j = 0; j < 4; j++)
          acc[i][j] = __builtin_amdgcn_mfma_f32_16x16x32_bf16(a[i], b[j], acc[i][j], 0, 0, 0);
    }
    __syncthreads();
  }

  // epilogue: val = acc + bias (+ h_old); store h_new; row stats; LN -> xn
#pragma unroll
  for (int j = 0; j < 4; j++) {
    int n = wid * 64 + j * 16 + lrow;
    float bvv = load_ext(bias, boff + n, flb);
#pragma unroll
    for (int i = 0; i < 2; i++) {
      int rl = i * 16 + lquad * 4;
#pragma unroll
      for (int r = 0; r < 4; r++) {
        float v = acc[i][j][r] + bvv;
        size_t idx = (size_t)(bm + rl + r) * 256 + n;
        if (RES) v += h[idx];
        acc[i][j][r] = v;
        h[idx] = v;
      }
    }
  }
  // per-row partial sums over this wave's 64 cols
#pragma unroll
  for (int i = 0; i < 2; i++) {
#pragma unroll
    for (int r = 0; r < 4; r++) {
      float s = acc[i][0][r] + acc[i][1][r] + acc[i][2][r] + acc[i][3][r];
      float q = acc[i][0][r] * acc[i][0][r] + acc[i][1][r] * acc[i][1][r]
              + acc[i][2][r] * acc[i][2][r] + acc[i][3][r] * acc[i][3][r];
#pragma unroll
      for (int o = 1; o <= 8; o <<= 1) {
        s += __shfl_xor(s, o);
        q += __shfl_xor(q, o);
      }
      if (lrow == 0) {
        int row = i * 16 + lquad * 4 + r;
        sums[row][wid] = s;
        sqs[row][wid] = q;
      }
    }
  }
  __syncthreads();
  if (tid < 32) {
    float s = sums[tid][0] + sums[tid][1] + sums[tid][2] + sums[tid][3];
    float q = sqs[tid][0] + sqs[tid][1] + sqs[tid][2] + sqs[tid][3];
    float mu = s * (1.f / 256.f);
    float var = q * (1.f / 256.f) - mu * mu;
    mus[tid] = mu;
    rss[tid] = rsqrtf(var + 1e-5f);
  }
  __syncthreads();
#pragma unroll
  for (int j = 0; j < 4; j++) {
    int n = wid * 64 + j * 16 + lrow;
    float gv = load_ext(g, goff + n, flg);
    float bb = load_ext(bv2, bvoff + n, flbv);
#pragma unroll
    for (int i = 0; i < 2; i++) {
#pragma unroll
      for (int r = 0; r < 4; r++) {
        int row = i * 16 + lquad * 4 + r;
        float xv = (acc[i][j][r] - mus[row]) * rss[row] * gv + bb;
        xn[(size_t)(bm + row) * 256 + n] = (bf16_t)xv;
      }
    }
  }
}

// ---------------------------------------------------------------------------
extern "C" void kernel_launch(void* const* d_in, const int* in_sizes, int n_in,
                              void* d_out, int out_size, void* d_ws, size_t ws_size,
                              hipStream_t stream) {
  const void* ei = d_in[1];

  char* ws = (char*)d_ws;
  size_t o = 0;
  int* flags  = (int*)(ws + o);    o += 256;
  int* deg    = (int*)(ws + o);    o += (size_t)N_NODES * 4;
  int* cursor = (int*)(ws + o);    o += (size_t)N_NODES * 4;
  int* off    = (int*)(ws + o);    o += 131328;
  int* csr    = (int*)(ws + o);    o += (size_t)N_EDGES * 4;
  bf16_t* wT  = (bf16_t*)(ws + o); o += (size_t)1638400 * 2;
  float* h    = (float*)(ws + o);  o += (size_t)N_NODES * 256 * 4;   // 32 MB
  bf16_t* xn  = (bf16_t*)(ws + o); o += (size_t)N_NODES * 256 * 2;   // 16 MB
  bf16_t* big = (bf16_t*)(ws + o); o += (size_t)N_NODES * 1024 * 2;  // 64 MB arena
  bf16_t* xb = big;                          // converted x (dead before QKV)
  unsigned char* qkv8 = (unsigned char*)big; // [N,768] fp8 q|k|v
  bf16_t* ab = xn;                           // agg aliases xn (row-exclusive in gemm_ln)
  bf16_t* ffnb = big;                        // [N,1024] bf16 (qkv8 dead then)

  hipMemsetAsync(deg, 0, N_NODES * 4, stream);
  hipMemsetAsync(cursor, 0, N_NODES * 4, stream);

  SniffArgs sa;
  for (int b = 0; b < 20; ++b) {
    sa.ptr[b] = d_in[b];
    sa.elems[b] = in_sizes[b];
    sa.kind[b] = (b == 1) ? 1 : 0;
  }
  sniff_all<<<20, 256, 0, stream>>>(sa, flags);

  convert_x<<<(N_NODES * 256) / 1024, 256, 0, stream>>>(d_in[0], xb, flags + 0);

  TransArgs ta;
  ta.flags = flags;
  int tiles = 0, idx = 0;
  auto add = [&](int slot, long soff, bf16_t* dst, int K, int N) {
    ta.d[idx].src = d_in[slot]; ta.d[idx].soff = soff; ta.d[idx].dst = dst;
    ta.d[idx].K = K; ta.d[idx].N = N; ta.d[idx].tile0 = tiles; ta.d[idx].fidx = slot;
    tiles += (K / 32) * (N / 32);
    ++idx;
  };
  bf16_t* wTin = wT;
  auto layer_base = [&](int l) { return wT + 65536 + (size_t)l * 786432; };
  add(2, 0, wTin, 256, 256);  // w_in
  for (int l = 0; l < 2; ++l) {
    bf16_t* base = layer_base(l);
    add(8,  (long)l * 65536,  base + 0,      256, 256);   // wq^T
    add(10, (long)l * 65536,  base + 65536,  256, 256);   // wk^T
    add(12, (long)l * 65536,  base + 131072, 256, 256);   // wv^T
    add(14, (long)l * 65536,  base + 196608, 256, 256);   // wo^T
    add(16, (long)l * 262144, base + 262144, 256, 1024);  // w1^T
    add(18, (long)l * 262144, base + 524288, 1024, 256);  // w2^T
  }
  transpose_many<<<tiles, 256, 0, stream>>>(ta);

  deg_count<<<N_EDGES / 256, 256, 0, stream>>>(ei, flags + 1, deg);
  scan_offsets<<<1, 1024, 0, stream>>>(deg, off);
  scatter_edges<<<N_EDGES / 256, 256, 0, stream>>>(ei, flags + 1, off, cursor, csr);

  // input proj + LN1(l0): h = x@w_in + b_in; xn = LN(h)
  gemm_ln<false><<<dim3(1, 1024), 256, 0, stream>>>(
      xb, wTin, d_in[3], 0, flags + 3,
      d_in[4], 0, flags + 4, d_in[5], 0, flags + 5, h, xn, 256);

  for (int l = 0; l < 2; ++l) {
    bf16_t* base = layer_base(l);
    // fused QKV -> fp8 [N,768]
    gemm_kernel<7, true><<<dim3(6, 256), 256, 0, stream>>>(
        xn, base, d_in[9], d_in[11], d_in[13], (long)l * 256,
        flags + 9, flags + 11, flags + 13, qkv8, nullptr, 768, 256);
    attn_k<<<N_NODES / 8, 256, 0, stream>>>(qkv8, off, csr, deg, ab);
    // o_proj + residual + LN2(l): h += ab@wo + bo; xn = LN(h)
    gemm_ln<true><<<dim3(1, 1024), 256, 0, stream>>>(
        ab, base + 196608, d_in[15], (long)l * 256, flags + 15,
        d_in[6], (long)l * 256, flags + 6, d_in[7], (long)l * 256, flags + 7,
        h, xn, 256);
    // FFN1: gelu -> bf16 [N,1024]
    gemm_kernel<1, false><<<dim3(8, 256), 256, 0, stream>>>(
        xn, base + 262144, d_in[17], nullptr, nullptr, (long)l * 1024,
        flags + 17, flags + 17, flags + 17, ffnb, nullptr, 1024, 256);
    if (l == 0) {
      // FFN2 + residual + LN1(l1): h += ffn; xn = LN(h)
      gemm_ln<true><<<dim3(1, 1024), 256, 0, stream>>>(
          ffnb, base + 524288, d_in[19], 0, flags + 19,
          d_in[4], 256, flags + 4, d_in[5], 256, flags + 5, h, xn, 1024);
    } else {
      // final: d_out = h + ffn
      gemm_kernel<4, false><<<dim3(2, 256), 256, 0, stream>>>(
          ffnb, base + 524288, d_in[19], nullptr, nullptr, (long)l * 256,
          flags + 19, flags + 19, flags + 19, h, (float*)d_out, 256, 1024);
    }
  }
}

// Round 8
// 538.859 us; speedup vs baseline: 1.4339x; 1.0540x over previous
//
#include <hip/hip_runtime.h>
#include <hip/hip_bf16.h>
#include <math.h>

typedef __bf16 bf16_t;
typedef __bf16 bf16x4 __attribute__((ext_vector_type(4)));
typedef __bf16 bf16x8 __attribute__((ext_vector_type(8)));
typedef float f32x4 __attribute__((ext_vector_type(4)));
typedef float f32x2 __attribute__((ext_vector_type(2)));

static constexpr int N_NODES = 32768;
static constexpr int N_EDGES = N_NODES * 16;

#define GLB_PTR(p) ((const __attribute__((address_space(1))) void*)(p))
#define LDS_PTR(p) ((__attribute__((address_space(3))) void*)(p))

// flag per tensor: 0 = fp32, 1 = bf16, 2 = all-zero (return 0 without reading)
__device__ __forceinline__ float load_ext(const void* p, long i, int fl) {
  if (fl == 2) return 0.f;
  return fl ? (float)((const bf16_t*)p)[i] : ((const float*)p)[i];
}

// ---------------------------------------------------------------------------
// Per-tensor dtype sniffer. kind 0 = float tensor, kind 1 = int tensor.
// ---------------------------------------------------------------------------
struct SniffArgs {
  const void* ptr[20];
  int elems[20];
  int kind[20];
};

__global__ __launch_bounds__(256) void sniff_all(SniffArgs a, int* flags) {
  int b = blockIdx.x;
  int t = threadIdx.x;
  __shared__ int s1[256], s2[256];
  if (a.kind[b] == 0) {
    const unsigned short* p = (const unsigned short*)a.ptr[b];
    int pairs = min(1024, a.elems[b] / 2);
    int sane = 0, nz = 0;
    for (int i = t; i < pairs; i += 256) {
      unsigned short we = p[2 * i], wo = p[2 * i + 1];
      if (we | wo) nz++;
      int e = (we >> 7) & 0xFF;
      if (we != 0 && e >= 100 && e <= 140) sane++;
    }
    s1[t] = sane; s2[t] = nz;
    __syncthreads();
    for (int o = 128; o >= 1; o >>= 1) {
      if (t < o) { s1[t] += s1[t + o]; s2[t] += s2[t + o]; }
      __syncthreads();
    }
    if (t == 0)
      flags[b] = (s2[0] == 0) ? 2 : ((2 * s1[0] > pairs) ? 1 : 0);
  } else {
    const int* ip = (const int*)a.ptr[b];
    int n = min(512, a.elems[b] / 2);
    int zeros = 0;
    for (int i = t; i < n; i += 256)
      if (ip[2 * i + 1] == 0) zeros++;
    s1[t] = zeros;
    __syncthreads();
    for (int o = 128; o >= 1; o >>= 1) {
      if (t < o) s1[t] += s1[t + o];
      __syncthreads();
    }
    if (t == 0) flags[b] = (s1[0] * 4 > n * 3) ? 1 : 0;
  }
}

__global__ __launch_bounds__(256) void convert_x(const void* src, bf16_t* dst,
                                                 const int* flagp) {
  int fl = *flagp;
  int i = (blockIdx.x * 256 + threadIdx.x) * 4;
  if (fl == 1) {
    *(int2*)(dst + i) = *(const int2*)((const bf16_t*)src + i);
  } else if (fl == 0) {
    float4 v = *(const float4*)((const float*)src + i);
    dst[i] = (bf16_t)v.x; dst[i + 1] = (bf16_t)v.y;
    dst[i + 2] = (bf16_t)v.z; dst[i + 3] = (bf16_t)v.w;
  } else {
    dst[i] = (bf16_t)0.f; dst[i + 1] = (bf16_t)0.f;
    dst[i + 2] = (bf16_t)0.f; dst[i + 3] = (bf16_t)0.f;
  }
}

// ---------------------------------------------------------------------------
// Batched 32x32 tile transpose: dst[n*K+k] = src[k*N+n], per-desc dtype flag.
// ---------------------------------------------------------------------------
struct TransDesc { const void* src; long soff; bf16_t* dst; int K; int N; int tile0; int fidx; };
struct TransArgs { TransDesc d[13]; const int* flags; };

__global__ __launch_bounds__(256) void transpose_many(TransArgs args) {
  __shared__ bf16_t tile[32][33];
  int blk = blockIdx.x;
  int i = 0;
#pragma unroll
  for (int j = 1; j < 13; ++j)
    if (blk >= args.d[j].tile0) i = j;
  TransDesc dd = args.d[i];
  int fl = args.flags[dd.fidx];
  int t = blk - dd.tile0;
  int tiles_x = dd.N / 32;
  int nbase = (t % tiles_x) * 32;
  int kbase = (t / tiles_x) * 32;
  int tx = threadIdx.x & 31, ty = threadIdx.x >> 5;
#pragma unroll
  for (int j = 0; j < 32; j += 8)
    tile[ty + j][tx] = (bf16_t)load_ext(dd.src, dd.soff + (long)(kbase + ty + j) * dd.N + nbase + tx, fl);
  __syncthreads();
#pragma unroll
  for (int j = 0; j < 32; j += 8)
    dd.dst[(size_t)(nbase + ty + j) * dd.K + kbase + tx] = tile[tx][ty + j];
}

// ---------------------------------------------------------------------------
// CSR build (edge_index int32 or int64 per flags[1])
// ---------------------------------------------------------------------------
__device__ __forceinline__ int edge_at(const void* ei, long i, int fl64) {
  return fl64 ? (int)((const long long*)ei)[i] : ((const int*)ei)[i];
}

__global__ __launch_bounds__(256) void deg_count(const void* __restrict__ ei,
                                                 const int* flagp,
                                                 int* __restrict__ deg) {
  int fl = *flagp;
  int e = blockIdx.x * 256 + threadIdx.x;
  if (e < N_EDGES) atomicAdd(&deg[edge_at(ei, (long)N_EDGES + e, fl)], 1);
}

__global__ __launch_bounds__(1024) void scan_offsets(const int* __restrict__ deg,
                                                     int* __restrict__ off) {
  __shared__ int s[1024];
  int t = threadIdx.x;
  int base = t * 32;
  int sum = 0;
  for (int i = 0; i < 32; ++i) sum += deg[base + i];
  s[t] = sum;
  __syncthreads();
  for (int o = 1; o < 1024; o <<= 1) {
    int v = (t >= o) ? s[t - o] : 0;
    __syncthreads();
    s[t] += v;
    __syncthreads();
  }
  int run = s[t] - sum;
  for (int i = 0; i < 32; ++i) { off[base + i] = run; run += deg[base + i]; }
  if (t == 1023) off[N_NODES] = run;
}

__global__ __launch_bounds__(256) void scatter_edges(const void* __restrict__ ei,
                                                     const int* flagp,
                                                     const int* __restrict__ off,
                                                     int* __restrict__ cursor,
                                                     int* __restrict__ csr) {
  int fl = *flagp;
  int e = blockIdx.x * 256 + threadIdx.x;
  if (e < N_EDGES) {
    int d = edge_at(ei, (long)N_EDGES + e, fl);
    int p = off[d] + atomicAdd(&cursor[d], 1);
    csr[p] = edge_at(ei, e, fl);
  }
}

// ---------------------------------------------------------------------------
// Attention v6: fp8 q/k/v, 2 nodes/wave (32 lanes/node, 8 dims/lane), packed
// cvt + f32x2 math, chunk-of-4 double-buffered prefetch with COMPILE-TIME
// constant buffer indices (full unroll) so all k/v buffers stay in VGPRs.
// ---------------------------------------------------------------------------
__device__ __forceinline__ int attn_slot(int j, int ne, int nid, int sl,
                                         const int* __restrict__ csr, int e0) {
  return (j == ne - 1) ? nid : (j < 32 ? __shfl(sl, j, 32) : csr[e0 + j]);
}

__device__ __forceinline__ void attn_load4(const unsigned char* __restrict__ qkv8,
                                           int c0, int ne, int nid, int sl,
                                           const int* __restrict__ csr, int e0, int l32,
                                           uint2 (&bk)[4], uint2 (&bv)[4]) {
#pragma unroll
  for (int t = 0; t < 4; ++t) {
    int j = c0 + t;
    if (j < ne) {
      int s = attn_slot(j, ne, nid, sl, csr, e0);
      const unsigned char* row = qkv8 + ((size_t)(s * 3) << 8) + l32 * 8;
      bk[t] = *(const uint2*)(row + 256);
      bv[t] = *(const uint2*)(row + 512);
    }
  }
}

__device__ __forceinline__ void attn_proc4(int c0, int ne,
                                           const f32x2& q01, const f32x2& q23,
                                           const f32x2& q45, const f32x2& q67,
                                           const uint2 (&bk)[4], const uint2 (&bv)[4],
                                           f32x2& a01, f32x2& a23, f32x2& a45, f32x2& a67,
                                           float& l) {
  const float C = 0.25503398f;  // (1/sqrt(32)) * log2(e)
#pragma unroll
  for (int t = 0; t < 4; ++t) {
    int j = c0 + t;
    if (j < ne) {
      uint2 kr = bk[t], vr = bv[t];
      f32x2 d = q01 * __builtin_amdgcn_cvt_pk_f32_fp8(kr.x, 0);
      d += q23 * __builtin_amdgcn_cvt_pk_f32_fp8(kr.x, 1);
      d += q45 * __builtin_amdgcn_cvt_pk_f32_fp8(kr.y, 0);
      d += q67 * __builtin_amdgcn_cvt_pk_f32_fp8(kr.y, 1);
      float p = d[0] + d[1];
      p += __shfl_xor(p, 1);
      p += __shfl_xor(p, 2);
      float ev = __builtin_amdgcn_exp2f(fminf(p * C, 86.f));
      f32x2 ev2 = {ev, ev};
      a01 += ev2 * __builtin_amdgcn_cvt_pk_f32_fp8(vr.x, 0);
      a23 += ev2 * __builtin_amdgcn_cvt_pk_f32_fp8(vr.x, 1);
      a45 += ev2 * __builtin_amdgcn_cvt_pk_f32_fp8(vr.y, 0);
      a67 += ev2 * __builtin_amdgcn_cvt_pk_f32_fp8(vr.y, 1);
      l += ev;
    }
  }
}

__global__ __launch_bounds__(256) void attn_k(const unsigned char* __restrict__ qkv8,
                                              const int* __restrict__ off,
                                              const int* __restrict__ csr,
                                              const int* __restrict__ deg,
                                              bf16_t* __restrict__ agg) {
  const int sub = threadIdx.x >> 5;              // 0..7 within block
  const int nid = blockIdx.x * 8 + sub;
  const int l32 = threadIdx.x & 31;              // lane within node group

  const unsigned char* nb = qkv8 + (size_t)((nid * 3) << 8);
  uint2 qw = *(const uint2*)(nb + l32 * 8);
  f32x2 q01 = __builtin_amdgcn_cvt_pk_f32_fp8(qw.x, 0);
  f32x2 q23 = __builtin_amdgcn_cvt_pk_f32_fp8(qw.x, 1);
  f32x2 q45 = __builtin_amdgcn_cvt_pk_f32_fp8(qw.y, 0);
  f32x2 q67 = __builtin_amdgcn_cvt_pk_f32_fp8(qw.y, 1);

  const int e0 = off[nid], e1 = off[nid + 1];
  const int ne = e1 - e0 + 1;                    // + self edge (last)
  int sl = (l32 < ne - 1) ? csr[e0 + l32] : nid; // neighbor list in regs (32 slots)

  uint2 kA[4], vA[4], kB[4], vB[4];
  float l = 0.f;
  f32x2 a01 = {0.f, 0.f}, a23 = {0.f, 0.f}, a45 = {0.f, 0.f}, a67 = {0.f, 0.f};

  attn_load4(qkv8, 0, ne, nid, sl, csr, e0, l32, kA, vA);
  for (int c = 0; c < ne; c += 8) {
    attn_load4(qkv8, c + 4, ne, nid, sl, csr, e0, l32, kB, vB);
    attn_proc4(c, ne, q01, q23, q45, q67, kA, vA, a01, a23, a45, a67, l);
    attn_load4(qkv8, c + 8, ne, nid, sl, csr, e0, l32, kA, vA);
    attn_proc4(c + 4, ne, q01, q23, q45, q67, kB, vB, a01, a23, a45, a67, l);
  }

  float inv = (deg[nid] > 0) ? 1.f / l : 0.f;
  bf16x8 ov;
  ov[0] = (bf16_t)(a01[0] * inv); ov[1] = (bf16_t)(a01[1] * inv);
  ov[2] = (bf16_t)(a23[0] * inv); ov[3] = (bf16_t)(a23[1] * inv);
  ov[4] = (bf16_t)(a45[0] * inv); ov[5] = (bf16_t)(a45[1] * inv);
  ov[6] = (bf16_t)(a67[0] * inv); ov[7] = (bf16_t)(a67[1] * inv);
  *(bf16x8*)(agg + (size_t)nid * 256 + l32 * 8) = ov;
}

// ---------------------------------------------------------------------------
// MFMA GEMM (128x128 tile, BK=64, global_load_lds + XOR swizzle).
// MODE 0: bf16 store; 1: gelu->bf16; 4: out2 = h + val (final); 7: fp8 store.
// (a) XCD-bijective block swizzle; (b) LDS-staged coalesced epilogue.
// ---------------------------------------------------------------------------
template <int MODE, bool FUSED3>
__global__ __launch_bounds__(256) void gemm_kernel(const bf16_t* __restrict__ A,
                                                   const bf16_t* __restrict__ BT,
                                                   const void* b0, const void* b1, const void* b2,
                                                   long boff,
                                                   const int* f0, const int* f1, const int* f2,
                                                   void* __restrict__ Cout,
                                                   float* __restrict__ out2,
                                                   int N, int K) {
  const int fl0 = *f0;
  const int fl1 = FUSED3 ? *f1 : 0;
  const int fl2 = FUSED3 ? *f2 : 0;

  // XCD-bijective swizzle: gridDim.y (=256) is a multiple of 8. Each XCD owns
  // a contiguous band of gridDim.y/8 A-panels and sweeps all gridDim.x blocks
  // of a panel consecutively (x fastest) -> panel is L2-resident per XCD.
  const int gx = gridDim.x;
  const int ybnd = gridDim.y >> 3;               // panels per XCD band
  int b = blockIdx.y * gx + blockIdx.x;
  int xcd = b & 7;
  int j0 = b >> 3;
  int yloc = j0 / gx;
  int xloc = j0 - yloc * gx;
  const int bm = (xcd * ybnd + yloc) * 128;
  const int bn = xloc * 128;

  const int tid = threadIdx.x;
  const int lane = tid & 63;
  const int wid = tid >> 6;
  const int wr = wid >> 1, wc = wid & 1;
  const int lrow = lane & 15;
  const int lquad = lane >> 4;
  const int l8 = lane >> 3;
  const int u = lane & 7;

  __shared__ __align__(16) char smem[32768];
  bf16_t* As = (bf16_t*)smem;                    // 16 KB
  bf16_t* Bs = (bf16_t*)(smem + 16384);          // 16 KB

  const bf16_t* aptr[4];
  const bf16_t* bptr[4];
#pragma unroll
  for (int c = 0; c < 4; ++c) {
    int row = (wid * 4 + c) * 8 + l8;
    int kseg = (u ^ l8) << 3;
    aptr[c] = A + (size_t)(bm + row) * K + kseg;
    bptr[c] = BT + (size_t)(bn + row) * K + kseg;
  }

  f32x4 acc[4][4];
#pragma unroll
  for (int i = 0; i < 4; i++)
#pragma unroll
    for (int j = 0; j < 4; j++)
#pragma unroll
      for (int r = 0; r < 4; r++) acc[i][j][r] = 0.f;

  for (int k0 = 0; k0 < K; k0 += 64) {
#pragma unroll
    for (int c = 0; c < 4; ++c) {
      int chunk = wid * 4 + c;
      __builtin_amdgcn_global_load_lds(GLB_PTR(aptr[c] + k0), LDS_PTR(As + chunk * 512), 16, 0, 0);
      __builtin_amdgcn_global_load_lds(GLB_PTR(bptr[c] + k0), LDS_PTR(Bs + chunk * 512), 16, 0, 0);
    }
    __syncthreads();
#pragma unroll
    for (int ks = 0; ks < 2; ++ks) {
      bf16x8 a[4], b2v[4];
#pragma unroll
      for (int i = 0; i < 4; i++) {
        int pu = ((ks * 4 + lquad) ^ (lrow & 7)) * 8;
        a[i] = *(const bf16x8*)(&As[(wr * 64 + i * 16 + lrow) * 64 + pu]);
        b2v[i] = *(const bf16x8*)(&Bs[(wc * 64 + i * 16 + lrow) * 64 + pu]);
      }
#pragma unroll
      for (int i = 0; i < 4; i++)
#pragma unroll
        for (int j = 0; j < 4; j++)
          acc[i][j] = __builtin_amdgcn_mfma_f32_16x16x32_bf16(a[i], b2v[j], acc[i][j], 0, 0, 0);
    }
    __syncthreads();
  }

  // Epilogue. C/D layout: col = lane&15, row = (lane>>4)*4 + reg.
  if (MODE == 4) {
    // fp32 path: 64B row segments are full sectors; store directly.
#pragma unroll
    for (int j = 0; j < 4; j++) {
      int n = bn + wc * 64 + j * 16 + lrow;
      float bv = load_ext(b0, boff + n, fl0);
#pragma unroll
      for (int i = 0; i < 4; i++) {
        int m0 = bm + wr * 64 + i * 16 + lquad * 4;
#pragma unroll
        for (int r = 0; r < 4; r++) {
          float val = acc[i][j][r] + bv;
          size_t idx = (size_t)(m0 + r) * N + n;
          out2[idx] = ((const float*)Cout)[idx] + val;
        }
      }
    }
  } else {
    // bf16/fp8 paths: stage 128x128 tile in LDS, then coalesced dwordx4 out.
#pragma unroll
    for (int j = 0; j < 4; j++) {
      int n = bn + wc * 64 + j * 16 + lrow;
      float bv;
      if (FUSED3) {
        int seg = n >> 8;
        const void* bp = (seg == 0) ? b0 : ((seg == 1) ? b1 : b2);
        int fl = (seg == 0) ? fl0 : ((seg == 1) ? fl1 : fl2);
        bv = load_ext(bp, boff + (n & 255), fl);
      } else {
        bv = load_ext(b0, boff + n, fl0);
      }
      int ncol = wc * 64 + j * 16 + lrow;
#pragma unroll
      for (int i = 0; i < 4; i++) {
        int m0 = wr * 64 + i * 16 + lquad * 4;
#pragma unroll
        for (int r = 0; r < 4; r++) {
          float val = acc[i][j][r] + bv;
          if (MODE == 0) {
            ((bf16_t*)smem)[(m0 + r) * 128 + ncol] = (bf16_t)val;
          } else if (MODE == 1) {
            float gl = 0.5f * val * (1.f + erff(val * 0.7071067811865475f));
            ((bf16_t*)smem)[(m0 + r) * 128 + ncol] = (bf16_t)gl;
          } else if (MODE == 7) {
            unsigned pk = __builtin_amdgcn_cvt_pk_fp8_f32(val, val, 0u, false);
            ((unsigned char*)smem)[(m0 + r) * 128 + ncol] = (unsigned char)(pk & 0xFF);
          }
        }
      }
    }
    __syncthreads();
    if (MODE == 7) {
      // 128x128 fp8 tile = 16 KB; per row 128 B = 8 lanes x 16 B.
      const unsigned char* ts = (const unsigned char*)smem;
#pragma unroll
      for (int p = 0; p < 4; ++p) {
        int row = p * 32 + (tid >> 3);
        int col = (tid & 7) * 16;
        *(int4*)((unsigned char*)Cout + (size_t)(bm + row) * N + bn + col) =
            *(const int4*)(ts + row * 128 + col);
      }
    } else {
      // 128x128 bf16 tile = 32 KB; per row 256 B = 16 lanes x 16 B.
      const bf16_t* ts = (const bf16_t*)smem;
#pragma unroll
      for (int p = 0; p < 8; ++p) {
        int row = p * 16 + (tid >> 4);
        int col = (tid & 15) * 8;
        *(int4*)((bf16_t*)Cout + (size_t)(bm + row) * N + bn + col) =
            *(const int4*)(ts + row * 128 + col);
      }
    }
  }
}

// ---------------------------------------------------------------------------
// GEMM + fused LayerNorm, v5: 64 rows x 256 cols per 512-thread block
// (8 waves = 2 row-groups x 4 col-groups, each wave 32x64, acc[2][4]).
// Same proven BK=64 / 128B-row / XOR-swizzle LDS layout as v2 (52 us), but
// the 32KB Bs panel is amortized over 64 output rows instead of 32: per-CU
// staging traffic and per-row barrier count halve, waves/CU unchanged at 16
// (2 blocks x 8 waves vs v2's 4 x 4). [Measured map: v1 64r/4w=68, v2
// 32r/4w=52, BK=32=94 (bank conflict), no-LDS=190 (serialized loads).]
// Writes h (fp32, += residual if RES) and xn = LN(h_new) (bf16).
// ---------------------------------------------------------------------------
template <bool RES>
__global__ __launch_bounds__(512) void gemm_ln(const bf16_t* __restrict__ A,
                                               const bf16_t* __restrict__ BT,
                                               const void* bias, long boff, const int* bfp,
                                               const void* g, long goff, const int* gfp,
                                               const void* bv2, long bvoff, const int* bvfp,
                                               float* __restrict__ h,
                                               bf16_t* __restrict__ xn,
                                               int K) {
  const int flb = *bfp, flg = *gfp, flbv = *bvfp;
  const int bm = blockIdx.y * 64;
  const int tid = threadIdx.x;
  const int lane = tid & 63;
  const int wid = tid >> 6;          // 0..7
  const int wr = wid >> 2;           // row-group 0..1
  const int wc = wid & 3;            // col-group 0..3
  const int lrow = lane & 15;
  const int lquad = lane >> 4;
  const int l8 = lane >> 3;
  const int u = lane & 7;

  __shared__ __align__(16) bf16_t As[64 * 64];    // 8 KB
  __shared__ __align__(16) bf16_t Bs[256 * 64];   // 32 KB
  __shared__ float sums[64][4], sqs[64][4];
  __shared__ float mus[64], rss[64];

  // A: 64 rows = 8 chunks of 8 rows; one chunk per wave (1 load/thread).
  const bf16_t* aptr = A + (size_t)(bm + wid * 8 + l8) * K + ((u ^ l8) << 3);
  // B: 256 rows = 32 chunks; 4 per wave.
  const bf16_t* bptr[4];
#pragma unroll
  for (int c = 0; c < 4; ++c) {
    int chunk = wid * 4 + c;
    bptr[c] = BT + (size_t)(chunk * 8 + l8) * K + ((u ^ l8) << 3);
  }

  f32x4 acc[2][4];
#pragma unroll
  for (int i = 0; i < 2; i++)
#pragma unroll
    for (int j = 0; j < 4; j++)
#pragma unroll
      for (int r = 0; r < 4; r++) acc[i][j][r] = 0.f;

  for (int k0 = 0; k0 < K; k0 += 64) {
    __builtin_amdgcn_global_load_lds(GLB_PTR(aptr + k0), LDS_PTR(As + wid * 512), 16, 0, 0);
#pragma unroll
    for (int c = 0; c < 4; ++c)
      __builtin_amdgcn_global_load_lds(GLB_PTR(bptr[c] + k0), LDS_PTR(Bs + (wid * 4 + c) * 512), 16, 0, 0);
    __syncthreads();
#pragma unroll
    for (int ks = 0; ks < 2; ++ks) {
      bf16x8 a[2], b[4];
      int pu = ((ks * 4 + lquad) ^ (lrow & 7)) * 8;
#pragma unroll
      for (int i = 0; i < 2; i++)
        a[i] = *(const bf16x8*)(&As[(wr * 32 + i * 16 + lrow) * 64 + pu]);
#pragma unroll
      for (int j = 0; j < 4; j++)
        b[j] = *(const bf16x8*)(&Bs[(wc * 64 + j * 16 + lrow) * 64 + pu]);
#pragma unroll
      for (int i = 0; i < 2; i++)
#pragma unroll
        for (int j = 0; j < 4; j++)
          acc[i][j] = __builtin_amdgcn_mfma_f32_16x16x32_bf16(a[i], b[j], acc[i][j], 0, 0, 0);
    }
    __syncthreads();
  }

  // epilogue: val = acc + bias (+ h_old); store h_new; row stats; LN -> xn
#pragma unroll
  for (int j = 0; j < 4; j++) {
    int n = wc * 64 + j * 16 + lrow;
    float bvv = load_ext(bias, boff + n, flb);
#pragma unroll
    for (int i = 0; i < 2; i++) {
      int rl = wr * 32 + i * 16 + lquad * 4;
#pragma unroll
      for (int r = 0; r < 4; r++) {
        float v = acc[i][j][r] + bvv;
        size_t idx = (size_t)(bm + rl + r) * 256 + n;
        if (RES) v += h[idx];
        acc[i][j][r] = v;
        h[idx] = v;
      }
    }
  }
  // per-row partial sums over this wave's 64 cols
#pragma unroll
  for (int i = 0; i < 2; i++) {
#pragma unroll
    for (int r = 0; r < 4; r++) {
      float s = acc[i][0][r] + acc[i][1][r] + acc[i][2][r] + acc[i][3][r];
      float q = acc[i][0][r] * acc[i][0][r] + acc[i][1][r] * acc[i][1][r]
              + acc[i][2][r] * acc[i][2][r] + acc[i][3][r] * acc[i][3][r];
#pragma unroll
      for (int o = 1; o <= 8; o <<= 1) {
        s += __shfl_xor(s, o);
        q += __shfl_xor(q, o);
      }
      if (lrow == 0) {
        int row = wr * 32 + i * 16 + lquad * 4 + r;
        sums[row][wc] = s;
        sqs[row][wc] = q;
      }
    }
  }
  __syncthreads();
  if (tid < 64) {
    float s = sums[tid][0] + sums[tid][1] + sums[tid][2] + sums[tid][3];
    float q = sqs[tid][0] + sqs[tid][1] + sqs[tid][2] + sqs[tid][3];
    float mu = s * (1.f / 256.f);
    float var = q * (1.f / 256.f) - mu * mu;
    mus[tid] = mu;
    rss[tid] = rsqrtf(var + 1e-5f);
  }
  __syncthreads();
#pragma unroll
  for (int j = 0; j < 4; j++) {
    int n = wc * 64 + j * 16 + lrow;
    float gv = load_ext(g, goff + n, flg);
    float bb = load_ext(bv2, bvoff + n, flbv);
#pragma unroll
    for (int i = 0; i < 2; i++) {
#pragma unroll
      for (int r = 0; r < 4; r++) {
        int row = wr * 32 + i * 16 + lquad * 4 + r;
        float xv = (acc[i][j][r] - mus[row]) * rss[row] * gv + bb;
        xn[(size_t)(bm + row) * 256 + n] = (bf16_t)xv;
      }
    }
  }
}

// ---------------------------------------------------------------------------
extern "C" void kernel_launch(void* const* d_in, const int* in_sizes, int n_in,
                              void* d_out, int out_size, void* d_ws, size_t ws_size,
                              hipStream_t stream) {
  const void* ei = d_in[1];

  char* ws = (char*)d_ws;
  size_t o = 0;
  int* flags  = (int*)(ws + o);    o += 256;
  int* deg    = (int*)(ws + o);    o += (size_t)N_NODES * 4;
  int* cursor = (int*)(ws + o);    o += (size_t)N_NODES * 4;
  int* off    = (int*)(ws + o);    o += 131328;
  int* csr    = (int*)(ws + o);    o += (size_t)N_EDGES * 4;
  bf16_t* wT  = (bf16_t*)(ws + o); o += (size_t)1638400 * 2;
  float* h    = (float*)(ws + o);  o += (size_t)N_NODES * 256 * 4;   // 32 MB
  bf16_t* xn  = (bf16_t*)(ws + o); o += (size_t)N_NODES * 256 * 2;   // 16 MB
  bf16_t* big = (bf16_t*)(ws + o); o += (size_t)N_NODES * 1024 * 2;  // 64 MB arena
  bf16_t* xb = big;                          // converted x (dead before QKV)
  unsigned char* qkv8 = (unsigned char*)big; // [N,768] fp8 q|k|v
  bf16_t* ab = xn;                           // agg aliases xn (row-exclusive in gemm_ln)
  bf16_t* ffnb = big;                        // [N,1024] bf16 (qkv8 dead then)

  hipMemsetAsync(deg, 0, N_NODES * 4, stream);
  hipMemsetAsync(cursor, 0, N_NODES * 4, stream);

  SniffArgs sa;
  for (int b = 0; b < 20; ++b) {
    sa.ptr[b] = d_in[b];
    sa.elems[b] = in_sizes[b];
    sa.kind[b] = (b == 1) ? 1 : 0;
  }
  sniff_all<<<20, 256, 0, stream>>>(sa, flags);

  convert_x<<<(N_NODES * 256) / 1024, 256, 0, stream>>>(d_in[0], xb, flags + 0);

  TransArgs ta;
  ta.flags = flags;
  int tiles = 0, idx = 0;
  auto add = [&](int slot, long soff, bf16_t* dst, int K, int N) {
    ta.d[idx].src = d_in[slot]; ta.d[idx].soff = soff; ta.d[idx].dst = dst;
    ta.d[idx].K = K; ta.d[idx].N = N; ta.d[idx].tile0 = tiles; ta.d[idx].fidx = slot;
    tiles += (K / 32) * (N / 32);
    ++idx;
  };
  bf16_t* wTin = wT;
  auto layer_base = [&](int l) { return wT + 65536 + (size_t)l * 786432; };
  add(2, 0, wTin, 256, 256);  // w_in
  for (int l = 0; l < 2; ++l) {
    bf16_t* base = layer_base(l);
    add(8,  (long)l * 65536,  base + 0,      256, 256);   // wq^T
    add(10, (long)l * 65536,  base + 65536,  256, 256);   // wk^T
    add(12, (long)l * 65536,  base + 131072, 256, 256);   // wv^T
    add(14, (long)l * 65536,  base + 196608, 256, 256);   // wo^T
    add(16, (long)l * 262144, base + 262144, 256, 1024);  // w1^T
    add(18, (long)l * 262144, base + 524288, 1024, 256);  // w2^T
  }
  transpose_many<<<tiles, 256, 0, stream>>>(ta);

  deg_count<<<N_EDGES / 256, 256, 0, stream>>>(ei, flags + 1, deg);
  scan_offsets<<<1, 1024, 0, stream>>>(deg, off);
  scatter_edges<<<N_EDGES / 256, 256, 0, stream>>>(ei, flags + 1, off, cursor, csr);

  // input proj + LN1(l0): h = x@w_in + b_in; xn = LN(h)
  gemm_ln<false><<<dim3(1, 512), 512, 0, stream>>>(
      xb, wTin, d_in[3], 0, flags + 3,
      d_in[4], 0, flags + 4, d_in[5], 0, flags + 5, h, xn, 256);

  for (int l = 0; l < 2; ++l) {
    bf16_t* base = layer_base(l);
    // fused QKV -> fp8 [N,768]
    gemm_kernel<7, true><<<dim3(6, 256), 256, 0, stream>>>(
        xn, base, d_in[9], d_in[11], d_in[13], (long)l * 256,
        flags + 9, flags + 11, flags + 13, qkv8, nullptr, 768, 256);
    attn_k<<<N_NODES / 8, 256, 0, stream>>>(qkv8, off, csr, deg, ab);
    // o_proj + residual + LN2(l): h += ab@wo + bo; xn = LN(h)
    gemm_ln<true><<<dim3(1, 512), 512, 0, stream>>>(
        ab, base + 196608, d_in[15], (long)l * 256, flags + 15,
        d_in[6], (long)l * 256, flags + 6, d_in[7], (long)l * 256, flags + 7,
        h, xn, 256);
    // FFN1: gelu -> bf16 [N,1024]
    gemm_kernel<1, false><<<dim3(8, 256), 256, 0, stream>>>(
        xn, base + 262144, d_in[17], nullptr, nullptr, (long)l * 1024,
        flags + 17, flags + 17, flags + 17, ffnb, nullptr, 1024, 256);
    if (l == 0) {
      // FFN2 + residual + LN1(l1): h += ffn; xn = LN(h)
      gemm_ln<true><<<dim3(1, 512), 512, 0, stream>>>(
          ffnb, base + 524288, d_in[19], 0, flags + 19,
          d_in[4], 256, flags + 4, d_in[5], 256, flags + 5, h, xn, 1024);
    } else {
      // final: d_out = h + ffn
      gemm_kernel<4, false><<<dim3(2, 256), 256, 0, stream>>>(
          ffnb, base + 524288, d_in[19], nullptr, nullptr, (long)l * 256,
          flags + 19, flags + 19, flags + 19, h, (float*)d_out, 256, 1024);
    }
  }
}

// Round 9
// 510.314 us; speedup vs baseline: 1.5141x; 1.0559x over previous
//
#include <hip/hip_runtime.h>
#include <hip/hip_bf16.h>
#include <math.h>

typedef __bf16 bf16_t;
typedef __bf16 bf16x4 __attribute__((ext_vector_type(4)));
typedef __bf16 bf16x8 __attribute__((ext_vector_type(8)));
typedef float f32x4 __attribute__((ext_vector_type(4)));
typedef float f32x2 __attribute__((ext_vector_type(2)));

static constexpr int N_NODES = 32768;
static constexpr int N_EDGES = N_NODES * 16;

#define GLB_PTR(p) ((const __attribute__((address_space(1))) void*)(p))
#define LDS_PTR(p) ((__attribute__((address_space(3))) void*)(p))

// flag per tensor: 0 = fp32, 1 = bf16, 2 = all-zero (return 0 without reading)
__device__ __forceinline__ float load_ext(const void* p, long i, int fl) {
  if (fl == 2) return 0.f;
  return fl ? (float)((const bf16_t*)p)[i] : ((const float*)p)[i];
}

// tanh-form GELU: ~8 VALU ops (2 transcendental) vs ~25 for erff.
// gelu(x) = 0.5x(1+tanh(0.79788456(x+0.044715x^3))) = x - x/(1+e^{2v})
// e^{2v} = exp2(x+0.044715x^3) * 2*0.79788456*log2(e) = exp2(u*2.3022081)
__device__ __forceinline__ float gelu_fast(float x) {
  float u = x * (1.f + 0.044715f * x * x);
  float E = __builtin_amdgcn_exp2f(u * 2.3022081f);
  return x - x * __builtin_amdgcn_rcpf(1.f + E);
}

// ---------------------------------------------------------------------------
// Per-tensor dtype sniffer. kind 0 = float tensor, kind 1 = int tensor.
// ---------------------------------------------------------------------------
struct SniffArgs {
  const void* ptr[20];
  int elems[20];
  int kind[20];
};

__global__ __launch_bounds__(256) void sniff_all(SniffArgs a, int* flags) {
  int b = blockIdx.x;
  int t = threadIdx.x;
  __shared__ int s1[256], s2[256];
  if (a.kind[b] == 0) {
    const unsigned short* p = (const unsigned short*)a.ptr[b];
    int pairs = min(1024, a.elems[b] / 2);
    int sane = 0, nz = 0;
    for (int i = t; i < pairs; i += 256) {
      unsigned short we = p[2 * i], wo = p[2 * i + 1];
      if (we | wo) nz++;
      int e = (we >> 7) & 0xFF;
      if (we != 0 && e >= 100 && e <= 140) sane++;
    }
    s1[t] = sane; s2[t] = nz;
    __syncthreads();
    for (int o = 128; o >= 1; o >>= 1) {
      if (t < o) { s1[t] += s1[t + o]; s2[t] += s2[t + o]; }
      __syncthreads();
    }
    if (t == 0)
      flags[b] = (s2[0] == 0) ? 2 : ((2 * s1[0] > pairs) ? 1 : 0);
  } else {
    const int* ip = (const int*)a.ptr[b];
    int n = min(512, a.elems[b] / 2);
    int zeros = 0;
    for (int i = t; i < n; i += 256)
      if (ip[2 * i + 1] == 0) zeros++;
    s1[t] = zeros;
    __syncthreads();
    for (int o = 128; o >= 1; o >>= 1) {
      if (t < o) s1[t] += s1[t + o];
      __syncthreads();
    }
    if (t == 0) flags[b] = (s1[0] * 4 > n * 3) ? 1 : 0;
  }
}

__global__ __launch_bounds__(256) void convert_x(const void* src, bf16_t* dst,
                                                 const int* flagp) {
  int fl = *flagp;
  int i = (blockIdx.x * 256 + threadIdx.x) * 4;
  if (fl == 1) {
    *(int2*)(dst + i) = *(const int2*)((const bf16_t*)src + i);
  } else if (fl == 0) {
    float4 v = *(const float4*)((const float*)src + i);
    dst[i] = (bf16_t)v.x; dst[i + 1] = (bf16_t)v.y;
    dst[i + 2] = (bf16_t)v.z; dst[i + 3] = (bf16_t)v.w;
  } else {
    dst[i] = (bf16_t)0.f; dst[i + 1] = (bf16_t)0.f;
    dst[i + 2] = (bf16_t)0.f; dst[i + 3] = (bf16_t)0.f;
  }
}

// ---------------------------------------------------------------------------
// Batched 32x32 tile transpose: dst[n*K+k] = src[k*N+n], per-desc dtype flag.
// ---------------------------------------------------------------------------
struct TransDesc { const void* src; long soff; bf16_t* dst; int K; int N; int tile0; int fidx; };
struct TransArgs { TransDesc d[13]; const int* flags; };

__global__ __launch_bounds__(256) void transpose_many(TransArgs args) {
  __shared__ bf16_t tile[32][33];
  int blk = blockIdx.x;
  int i = 0;
#pragma unroll
  for (int j = 1; j < 13; ++j)
    if (blk >= args.d[j].tile0) i = j;
  TransDesc dd = args.d[i];
  int fl = args.flags[dd.fidx];
  int t = blk - dd.tile0;
  int tiles_x = dd.N / 32;
  int nbase = (t % tiles_x) * 32;
  int kbase = (t / tiles_x) * 32;
  int tx = threadIdx.x & 31, ty = threadIdx.x >> 5;
#pragma unroll
  for (int j = 0; j < 32; j += 8)
    tile[ty + j][tx] = (bf16_t)load_ext(dd.src, dd.soff + (long)(kbase + ty + j) * dd.N + nbase + tx, fl);
  __syncthreads();
#pragma unroll
  for (int j = 0; j < 32; j += 8)
    dd.dst[(size_t)(nbase + ty + j) * dd.K + kbase + tx] = tile[tx][ty + j];
}

// ---------------------------------------------------------------------------
// CSR build (edge_index int32 or int64 per flags[1])
// ---------------------------------------------------------------------------
__device__ __forceinline__ int edge_at(const void* ei, long i, int fl64) {
  return fl64 ? (int)((const long long*)ei)[i] : ((const int*)ei)[i];
}

__global__ __launch_bounds__(256) void deg_count(const void* __restrict__ ei,
                                                 const int* flagp,
                                                 int* __restrict__ deg) {
  int fl = *flagp;
  int e = blockIdx.x * 256 + threadIdx.x;
  if (e < N_EDGES) atomicAdd(&deg[edge_at(ei, (long)N_EDGES + e, fl)], 1);
}

__global__ __launch_bounds__(1024) void scan_offsets(const int* __restrict__ deg,
                                                     int* __restrict__ off) {
  __shared__ int s[1024];
  int t = threadIdx.x;
  int base = t * 32;
  int sum = 0;
  for (int i = 0; i < 32; ++i) sum += deg[base + i];
  s[t] = sum;
  __syncthreads();
  for (int o = 1; o < 1024; o <<= 1) {
    int v = (t >= o) ? s[t - o] : 0;
    __syncthreads();
    s[t] += v;
    __syncthreads();
  }
  int run = s[t] - sum;
  for (int i = 0; i < 32; ++i) { off[base + i] = run; run += deg[base + i]; }
  if (t == 1023) off[N_NODES] = run;
}

__global__ __launch_bounds__(256) void scatter_edges(const void* __restrict__ ei,
                                                     const int* flagp,
                                                     const int* __restrict__ off,
                                                     int* __restrict__ cursor,
                                                     int* __restrict__ csr) {
  int fl = *flagp;
  int e = blockIdx.x * 256 + threadIdx.x;
  if (e < N_EDGES) {
    int d = edge_at(ei, (long)N_EDGES + e, fl);
    int p = off[d] + atomicAdd(&cursor[d], 1);
    csr[p] = edge_at(ei, e, fl);
  }
}

// ---------------------------------------------------------------------------
// Attention v6: fp8 q/k/v, 2 nodes/wave (32 lanes/node, 8 dims/lane), packed
// cvt + f32x2 math, chunk-of-4 double-buffered prefetch with COMPILE-TIME
// constant buffer indices (full unroll) so all k/v buffers stay in VGPRs.
// ---------------------------------------------------------------------------
__device__ __forceinline__ int attn_slot(int j, int ne, int nid, int sl,
                                         const int* __restrict__ csr, int e0) {
  return (j == ne - 1) ? nid : (j < 32 ? __shfl(sl, j, 32) : csr[e0 + j]);
}

__device__ __forceinline__ void attn_load4(const unsigned char* __restrict__ qkv8,
                                           int c0, int ne, int nid, int sl,
                                           const int* __restrict__ csr, int e0, int l32,
                                           uint2 (&bk)[4], uint2 (&bv)[4]) {
#pragma unroll
  for (int t = 0; t < 4; ++t) {
    int j = c0 + t;
    if (j < ne) {
      int s = attn_slot(j, ne, nid, sl, csr, e0);
      const unsigned char* row = qkv8 + ((size_t)(s * 3) << 8) + l32 * 8;
      bk[t] = *(const uint2*)(row + 256);
      bv[t] = *(const uint2*)(row + 512);
    }
  }
}

__device__ __forceinline__ void attn_proc4(int c0, int ne,
                                           const f32x2& q01, const f32x2& q23,
                                           const f32x2& q45, const f32x2& q67,
                                           const uint2 (&bk)[4], const uint2 (&bv)[4],
                                           f32x2& a01, f32x2& a23, f32x2& a45, f32x2& a67,
                                           float& l) {
  const float C = 0.25503398f;  // (1/sqrt(32)) * log2(e)
#pragma unroll
  for (int t = 0; t < 4; ++t) {
    int j = c0 + t;
    if (j < ne) {
      uint2 kr = bk[t], vr = bv[t];
      f32x2 d = q01 * __builtin_amdgcn_cvt_pk_f32_fp8(kr.x, 0);
      d += q23 * __builtin_amdgcn_cvt_pk_f32_fp8(kr.x, 1);
      d += q45 * __builtin_amdgcn_cvt_pk_f32_fp8(kr.y, 0);
      d += q67 * __builtin_amdgcn_cvt_pk_f32_fp8(kr.y, 1);
      float p = d[0] + d[1];
      p += __shfl_xor(p, 1);
      p += __shfl_xor(p, 2);
      float ev = __builtin_amdgcn_exp2f(fminf(p * C, 86.f));
      f32x2 ev2 = {ev, ev};
      a01 += ev2 * __builtin_amdgcn_cvt_pk_f32_fp8(vr.x, 0);
      a23 += ev2 * __builtin_amdgcn_cvt_pk_f32_fp8(vr.x, 1);
      a45 += ev2 * __builtin_amdgcn_cvt_pk_f32_fp8(vr.y, 0);
      a67 += ev2 * __builtin_amdgcn_cvt_pk_f32_fp8(vr.y, 1);
      l += ev;
    }
  }
}

__global__ __launch_bounds__(256) void attn_k(const unsigned char* __restrict__ qkv8,
                                              const int* __restrict__ off,
                                              const int* __restrict__ csr,
                                              const int* __restrict__ deg,
                                              bf16_t* __restrict__ agg) {
  const int sub = threadIdx.x >> 5;              // 0..7 within block
  const int nid = blockIdx.x * 8 + sub;
  const int l32 = threadIdx.x & 31;              // lane within node group

  const unsigned char* nb = qkv8 + (size_t)((nid * 3) << 8);
  uint2 qw = *(const uint2*)(nb + l32 * 8);
  f32x2 q01 = __builtin_amdgcn_cvt_pk_f32_fp8(qw.x, 0);
  f32x2 q23 = __builtin_amdgcn_cvt_pk_f32_fp8(qw.x, 1);
  f32x2 q45 = __builtin_amdgcn_cvt_pk_f32_fp8(qw.y, 0);
  f32x2 q67 = __builtin_amdgcn_cvt_pk_f32_fp8(qw.y, 1);

  const int e0 = off[nid], e1 = off[nid + 1];
  const int ne = e1 - e0 + 1;                    // + self edge (last)
  int sl = (l32 < ne - 1) ? csr[e0 + l32] : nid; // neighbor list in regs (32 slots)

  uint2 kA[4], vA[4], kB[4], vB[4];
  float l = 0.f;
  f32x2 a01 = {0.f, 0.f}, a23 = {0.f, 0.f}, a45 = {0.f, 0.f}, a67 = {0.f, 0.f};

  attn_load4(qkv8, 0, ne, nid, sl, csr, e0, l32, kA, vA);
  for (int c = 0; c < ne; c += 8) {
    attn_load4(qkv8, c + 4, ne, nid, sl, csr, e0, l32, kB, vB);
    attn_proc4(c, ne, q01, q23, q45, q67, kA, vA, a01, a23, a45, a67, l);
    attn_load4(qkv8, c + 8, ne, nid, sl, csr, e0, l32, kA, vA);
    attn_proc4(c + 4, ne, q01, q23, q45, q67, kB, vB, a01, a23, a45, a67, l);
  }

  float inv = (deg[nid] > 0) ? 1.f / l : 0.f;
  bf16x8 ov;
  ov[0] = (bf16_t)(a01[0] * inv); ov[1] = (bf16_t)(a01[1] * inv);
  ov[2] = (bf16_t)(a23[0] * inv); ov[3] = (bf16_t)(a23[1] * inv);
  ov[4] = (bf16_t)(a45[0] * inv); ov[5] = (bf16_t)(a45[1] * inv);
  ov[6] = (bf16_t)(a67[0] * inv); ov[7] = (bf16_t)(a67[1] * inv);
  *(bf16x8*)(agg + (size_t)nid * 256 + l32 * 8) = ov;
}

// ---------------------------------------------------------------------------
// MFMA GEMM (128x128 tile, BK=64, global_load_lds + XOR swizzle).
// MODE 0: bf16 store; 1: gelu->bf16; 4: out2 = h + val (final); 7: fp8 store.
// (a) XCD-bijective block swizzle; (b) LDS-staged coalesced epilogue with
// row-quad XOR swizzle (v1 staging had 4-way bank conflicts: lane-quads
// write rows 4 apart = 1024B stride = same banks); (c) MODE 1 uses
// gelu_fast (erff was ~25 VALU ops/elem, 53% VALUBusy on FFN1).
// ---------------------------------------------------------------------------
template <int MODE, bool FUSED3>
__global__ __launch_bounds__(256) void gemm_kernel(const bf16_t* __restrict__ A,
                                                   const bf16_t* __restrict__ BT,
                                                   const void* b0, const void* b1, const void* b2,
                                                   long boff,
                                                   const int* f0, const int* f1, const int* f2,
                                                   void* __restrict__ Cout,
                                                   float* __restrict__ out2,
                                                   int N, int K) {
  const int fl0 = *f0;
  const int fl1 = FUSED3 ? *f1 : 0;
  const int fl2 = FUSED3 ? *f2 : 0;

  // XCD-bijective swizzle: gridDim.y (=256) is a multiple of 8. Each XCD owns
  // a contiguous band of gridDim.y/8 A-panels and sweeps all gridDim.x blocks
  // of a panel consecutively (x fastest) -> panel is L2-resident per XCD.
  const int gx = gridDim.x;
  const int ybnd = gridDim.y >> 3;               // panels per XCD band
  int b = blockIdx.y * gx + blockIdx.x;
  int xcd = b & 7;
  int j0 = b >> 3;
  int yloc = j0 / gx;
  int xloc = j0 - yloc * gx;
  const int bm = (xcd * ybnd + yloc) * 128;
  const int bn = xloc * 128;

  const int tid = threadIdx.x;
  const int lane = tid & 63;
  const int wid = tid >> 6;
  const int wr = wid >> 1, wc = wid & 1;
  const int lrow = lane & 15;
  const int lquad = lane >> 4;
  const int l8 = lane >> 3;
  const int u = lane & 7;

  __shared__ __align__(16) char smem[32768];
  bf16_t* As = (bf16_t*)smem;                    // 16 KB
  bf16_t* Bs = (bf16_t*)(smem + 16384);          // 16 KB

  const bf16_t* aptr[4];
  const bf16_t* bptr[4];
#pragma unroll
  for (int c = 0; c < 4; ++c) {
    int row = (wid * 4 + c) * 8 + l8;
    int kseg = (u ^ l8) << 3;
    aptr[c] = A + (size_t)(bm + row) * K + kseg;
    bptr[c] = BT + (size_t)(bn + row) * K + kseg;
  }

  f32x4 acc[4][4];
#pragma unroll
  for (int i = 0; i < 4; i++)
#pragma unroll
    for (int j = 0; j < 4; j++)
#pragma unroll
      for (int r = 0; r < 4; r++) acc[i][j][r] = 0.f;

  for (int k0 = 0; k0 < K; k0 += 64) {
#pragma unroll
    for (int c = 0; c < 4; ++c) {
      int chunk = wid * 4 + c;
      __builtin_amdgcn_global_load_lds(GLB_PTR(aptr[c] + k0), LDS_PTR(As + chunk * 512), 16, 0, 0);
      __builtin_amdgcn_global_load_lds(GLB_PTR(bptr[c] + k0), LDS_PTR(Bs + chunk * 512), 16, 0, 0);
    }
    __syncthreads();
#pragma unroll
    for (int ks = 0; ks < 2; ++ks) {
      bf16x8 a[4], b2v[4];
#pragma unroll
      for (int i = 0; i < 4; i++) {
        int pu = ((ks * 4 + lquad) ^ (lrow & 7)) * 8;
        a[i] = *(const bf16x8*)(&As[(wr * 64 + i * 16 + lrow) * 64 + pu]);
        b2v[i] = *(const bf16x8*)(&Bs[(wc * 64 + i * 16 + lrow) * 64 + pu]);
      }
#pragma unroll
      for (int i = 0; i < 4; i++)
#pragma unroll
        for (int j = 0; j < 4; j++)
          acc[i][j] = __builtin_amdgcn_mfma_f32_16x16x32_bf16(a[i], b2v[j], acc[i][j], 0, 0, 0);
    }
    __syncthreads();
  }

  // Epilogue. C/D layout: col = lane&15, row = (lane>>4)*4 + reg.
  if (MODE == 4) {
    // fp32 path: 64B row segments are full sectors; store directly.
#pragma unroll
    for (int j = 0; j < 4; j++) {
      int n = bn + wc * 64 + j * 16 + lrow;
      float bv = load_ext(b0, boff + n, fl0);
#pragma unroll
      for (int i = 0; i < 4; i++) {
        int m0 = bm + wr * 64 + i * 16 + lquad * 4;
#pragma unroll
        for (int r = 0; r < 4; r++) {
          float val = acc[i][j][r] + bv;
          size_t idx = (size_t)(m0 + r) * N + n;
          out2[idx] = ((const float*)Cout)[idx] + val;
        }
      }
    }
  } else {
    // bf16/fp8 paths: stage 128x128 tile in LDS (row-quad XOR swizzle to
    // spread lane-quads across bank groups), then coalesced dwordx4 out.
#pragma unroll
    for (int j = 0; j < 4; j++) {
      int n = bn + wc * 64 + j * 16 + lrow;
      float bv;
      if (FUSED3) {
        int seg = n >> 8;
        const void* bp = (seg == 0) ? b0 : ((seg == 1) ? b1 : b2);
        int fl = (seg == 0) ? fl0 : ((seg == 1) ? fl1 : fl2);
        bv = load_ext(bp, boff + (n & 255), fl);
      } else {
        bv = load_ext(b0, boff + n, fl0);
      }
      int ncol = wc * 64 + j * 16 + lrow;
#pragma unroll
      for (int i = 0; i < 4; i++) {
        int m0 = wr * 64 + i * 16 + lquad * 4;
#pragma unroll
        for (int r = 0; r < 4; r++) {
          float val = acc[i][j][r] + bv;
          int row = m0 + r;
          int sw = ((row >> 2) & 3) << 4;   // 16-elem (bf16) / 16-byte (fp8) blocks
          if (MODE == 0) {
            ((bf16_t*)smem)[row * 128 + (ncol ^ sw)] = (bf16_t)val;
          } else if (MODE == 1) {
            ((bf16_t*)smem)[row * 128 + (ncol ^ sw)] = (bf16_t)gelu_fast(val);
          } else if (MODE == 7) {
            unsigned pk = __builtin_amdgcn_cvt_pk_fp8_f32(val, val, 0u, false);
            ((unsigned char*)smem)[row * 128 + (ncol ^ sw)] = (unsigned char)(pk & 0xFF);
          }
        }
      }
    }
    __syncthreads();
    if (MODE == 7) {
      // 128x128 fp8 tile = 16 KB; per row 128 B = 8 lanes x 16 B.
      const unsigned char* ts = (const unsigned char*)smem;
#pragma unroll
      for (int p = 0; p < 4; ++p) {
        int row = p * 32 + (tid >> 3);
        int sw = ((row >> 2) & 3) << 4;
        int col = ((tid & 7) * 16) ^ sw;
        *(int4*)((unsigned char*)Cout + (size_t)(bm + row) * N + bn + (((tid & 7) * 16))) =
            *(const int4*)(ts + row * 128 + col);
      }
    } else {
      // 128x128 bf16 tile = 32 KB; per row 256 B = 16 lanes x 16 B.
      const bf16_t* ts = (const bf16_t*)smem;
#pragma unroll
      for (int p = 0; p < 8; ++p) {
        int row = p * 16 + (tid >> 4);
        int sw = ((row >> 2) & 3) << 4;
        int col = ((tid & 15) * 8) ^ sw;
        *(int4*)((bf16_t*)Cout + (size_t)(bm + row) * N + bn + ((tid & 15) * 8)) =
            *(const int4*)(ts + row * 128 + col);
      }
    }
  }
}

// ---------------------------------------------------------------------------
// GEMM + fused LayerNorm, v5: 64 rows x 256 cols per 512-thread block
// (8 waves = 2 row-groups x 4 col-groups, each wave 32x64, acc[2][4]).
// Same proven BK=64 / 128B-row / XOR-swizzle LDS layout as v2 (52 us), but
// the 32KB Bs panel is amortized over 64 output rows instead of 32: per-CU
// staging traffic and per-row barrier count halve, waves/CU unchanged at 16
// (2 blocks x 8 waves vs v2's 4 x 4). [Measured map: v1 64r/4w=68, v2
// 32r/4w=52, BK=32=94 (bank conflict), no-LDS=190 (serialized loads).]
// Writes h (fp32, += residual if RES) and xn = LN(h_new) (bf16).
// ---------------------------------------------------------------------------
template <bool RES>
__global__ __launch_bounds__(512) void gemm_ln(const bf16_t* __restrict__ A,
                                               const bf16_t* __restrict__ BT,
                                               const void* bias, long boff, const int* bfp,
                                               const void* g, long goff, const int* gfp,
                                               const void* bv2, long bvoff, const int* bvfp,
                                               float* __restrict__ h,
                                               bf16_t* __restrict__ xn,
                                               int K) {
  const int flb = *bfp, flg = *gfp, flbv = *bvfp;
  const int bm = blockIdx.y * 64;
  const int tid = threadIdx.x;
  const int lane = tid & 63;
  const int wid = tid >> 6;          // 0..7
  const int wr = wid >> 2;           // row-group 0..1
  const int wc = wid & 3;            // col-group 0..3
  const int lrow = lane & 15;
  const int lquad = lane >> 4;
  const int l8 = lane >> 3;
  const int u = lane & 7;

  __shared__ __align__(16) bf16_t As[64 * 64];    // 8 KB
  __shared__ __align__(16) bf16_t Bs[256 * 64];   // 32 KB
  __shared__ float sums[64][4], sqs[64][4];
  __shared__ float mus[64], rss[64];

  // A: 64 rows = 8 chunks of 8 rows; one chunk per wave (1 load/thread).
  const bf16_t* aptr = A + (size_t)(bm + wid * 8 + l8) * K + ((u ^ l8) << 3);
  // B: 256 rows = 32 chunks; 4 per wave.
  const bf16_t* bptr[4];
#pragma unroll
  for (int c = 0; c < 4; ++c) {
    int chunk = wid * 4 + c;
    bptr[c] = BT + (size_t)(chunk * 8 + l8) * K + ((u ^ l8) << 3);
  }

  f32x4 acc[2][4];
#pragma unroll
  for (int i = 0; i < 2; i++)
#pragma unroll
    for (int j = 0; j < 4; j++)
#pragma unroll
      for (int r = 0; r < 4; r++) acc[i][j][r] = 0.f;

  for (int k0 = 0; k0 < K; k0 += 64) {
    __builtin_amdgcn_global_load_lds(GLB_PTR(aptr + k0), LDS_PTR(As + wid * 512), 16, 0, 0);
#pragma unroll
    for (int c = 0; c < 4; ++c)
      __builtin_amdgcn_global_load_lds(GLB_PTR(bptr[c] + k0), LDS_PTR(Bs + (wid * 4 + c) * 512), 16, 0, 0);
    __syncthreads();
#pragma unroll
    for (int ks = 0; ks < 2; ++ks) {
      bf16x8 a[2], b[4];
      int pu = ((ks * 4 + lquad) ^ (lrow & 7)) * 8;
#pragma unroll
      for (int i = 0; i < 2; i++)
        a[i] = *(const bf16x8*)(&As[(wr * 32 + i * 16 + lrow) * 64 + pu]);
#pragma unroll
      for (int j = 0; j < 4; j++)
        b[j] = *(const bf16x8*)(&Bs[(wc * 64 + j * 16 + lrow) * 64 + pu]);
#pragma unroll
      for (int i = 0; i < 2; i++)
#pragma unroll
        for (int j = 0; j < 4; j++)
          acc[i][j] = __builtin_amdgcn_mfma_f32_16x16x32_bf16(a[i], b[j], acc[i][j], 0, 0, 0);
    }
    __syncthreads();
  }

  // epilogue: val = acc + bias (+ h_old); store h_new; row stats; LN -> xn
#pragma unroll
  for (int j = 0; j < 4; j++) {
    int n = wc * 64 + j * 16 + lrow;
    float bvv = load_ext(bias, boff + n, flb);
#pragma unroll
    for (int i = 0; i < 2; i++) {
      int rl = wr * 32 + i * 16 + lquad * 4;
#pragma unroll
      for (int r = 0; r < 4; r++) {
        float v = acc[i][j][r] + bvv;
        size_t idx = (size_t)(bm + rl + r) * 256 + n;
        if (RES) v += h[idx];
        acc[i][j][r] = v;
        h[idx] = v;
      }
    }
  }
  // per-row partial sums over this wave's 64 cols
#pragma unroll
  for (int i = 0; i < 2; i++) {
#pragma unroll
    for (int r = 0; r < 4; r++) {
      float s = acc[i][0][r] + acc[i][1][r] + acc[i][2][r] + acc[i][3][r];
      float q = acc[i][0][r] * acc[i][0][r] + acc[i][1][r] * acc[i][1][r]
              + acc[i][2][r] * acc[i][2][r] + acc[i][3][r] * acc[i][3][r];
#pragma unroll
      for (int o = 1; o <= 8; o <<= 1) {
        s += __shfl_xor(s, o);
        q += __shfl_xor(q, o);
      }
      if (lrow == 0) {
        int row = wr * 32 + i * 16 + lquad * 4 + r;
        sums[row][wc] = s;
        sqs[row][wc] = q;
      }
    }
  }
  __syncthreads();
  if (tid < 64) {
    float s = sums[tid][0] + sums[tid][1] + sums[tid][2] + sums[tid][3];
    float q = sqs[tid][0] + sqs[tid][1] + sqs[tid][2] + sqs[tid][3];
    float mu = s * (1.f / 256.f);
    float var = q * (1.f / 256.f) - mu * mu;
    mus[tid] = mu;
    rss[tid] = rsqrtf(var + 1e-5f);
  }
  __syncthreads();
#pragma unroll
  for (int j = 0; j < 4; j++) {
    int n = wc * 64 + j * 16 + lrow;
    float gv = load_ext(g, goff + n, flg);
    float bb = load_ext(bv2, bvoff + n, flbv);
#pragma unroll
    for (int i = 0; i < 2; i++) {
#pragma unroll
      for (int r = 0; r < 4; r++) {
        int row = wr * 32 + i * 16 + lquad * 4 + r;
        float xv = (acc[i][j][r] - mus[row]) * rss[row] * gv + bb;
        xn[(size_t)(bm + row) * 256 + n] = (bf16_t)xv;
      }
    }
  }
}

// ---------------------------------------------------------------------------
extern "C" void kernel_launch(void* const* d_in, const int* in_sizes, int n_in,
                              void* d_out, int out_size, void* d_ws, size_t ws_size,
                              hipStream_t stream) {
  const void* ei = d_in[1];

  char* ws = (char*)d_ws;
  size_t o = 0;
  int* flags  = (int*)(ws + o);    o += 256;
  int* deg    = (int*)(ws + o);    o += (size_t)N_NODES * 4;
  int* cursor = (int*)(ws + o);    o += (size_t)N_NODES * 4;
  int* off    = (int*)(ws + o);    o += 131328;
  int* csr    = (int*)(ws + o);    o += (size_t)N_EDGES * 4;
  bf16_t* wT  = (bf16_t*)(ws + o); o += (size_t)1638400 * 2;
  float* h    = (float*)(ws + o);  o += (size_t)N_NODES * 256 * 4;   // 32 MB
  bf16_t* xn  = (bf16_t*)(ws + o); o += (size_t)N_NODES * 256 * 2;   // 16 MB
  bf16_t* big = (bf16_t*)(ws + o); o += (size_t)N_NODES * 1024 * 2;  // 64 MB arena
  bf16_t* xb = big;                          // converted x (dead before QKV)
  unsigned char* qkv8 = (unsigned char*)big; // [N,768] fp8 q|k|v
  bf16_t* ab = xn;                           // agg aliases xn (row-exclusive in gemm_ln)
  bf16_t* ffnb = big;                        // [N,1024] bf16 (qkv8 dead then)

  hipMemsetAsync(deg, 0, N_NODES * 4, stream);
  hipMemsetAsync(cursor, 0, N_NODES * 4, stream);

  SniffArgs sa;
  for (int b = 0; b < 20; ++b) {
    sa.ptr[b] = d_in[b];
    sa.elems[b] = in_sizes[b];
    sa.kind[b] = (b == 1) ? 1 : 0;
  }
  sniff_all<<<20, 256, 0, stream>>>(sa, flags);

  convert_x<<<(N_NODES * 256) / 1024, 256, 0, stream>>>(d_in[0], xb, flags + 0);

  TransArgs ta;
  ta.flags = flags;
  int tiles = 0, idx = 0;
  auto add = [&](int slot, long soff, bf16_t* dst, int K, int N) {
    ta.d[idx].src = d_in[slot]; ta.d[idx].soff = soff; ta.d[idx].dst = dst;
    ta.d[idx].K = K; ta.d[idx].N = N; ta.d[idx].tile0 = tiles; ta.d[idx].fidx = slot;
    tiles += (K / 32) * (N / 32);
    ++idx;
  };
  bf16_t* wTin = wT;
  auto layer_base = [&](int l) { return wT + 65536 + (size_t)l * 786432; };
  add(2, 0, wTin, 256, 256);  // w_in
  for (int l = 0; l < 2; ++l) {
    bf16_t* base = layer_base(l);
    add(8,  (long)l * 65536,  base + 0,      256, 256);   // wq^T
    add(10, (long)l * 65536,  base + 65536,  256, 256);   // wk^T
    add(12, (long)l * 65536,  base + 131072, 256, 256);   // wv^T
    add(14, (long)l * 65536,  base + 196608, 256, 256);   // wo^T
    add(16, (long)l * 262144, base + 262144, 256, 1024);  // w1^T
    add(18, (long)l * 262144, base + 524288, 1024, 256);  // w2^T
  }
  transpose_many<<<tiles, 256, 0, stream>>>(ta);

  deg_count<<<N_EDGES / 256, 256, 0, stream>>>(ei, flags + 1, deg);
  scan_offsets<<<1, 1024, 0, stream>>>(deg, off);
  scatter_edges<<<N_EDGES / 256, 256, 0, stream>>>(ei, flags + 1, off, cursor, csr);

  // input proj + LN1(l0): h = x@w_in + b_in; xn = LN(h)
  gemm_ln<false><<<dim3(1, 512), 512, 0, stream>>>(
      xb, wTin, d_in[3], 0, flags + 3,
      d_in[4], 0, flags + 4, d_in[5], 0, flags + 5, h, xn, 256);

  for (int l = 0; l < 2; ++l) {
    bf16_t* base = layer_base(l);
    // fused QKV -> fp8 [N,768]
    gemm_kernel<7, true><<<dim3(6, 256), 256, 0, stream>>>(
        xn, base, d_in[9], d_in[11], d_in[13], (long)l * 256,
        flags + 9, flags + 11, flags + 13, qkv8, nullptr, 768, 256);
    attn_k<<<N_NODES / 8, 256, 0, stream>>>(qkv8, off, csr, deg, ab);
    // o_proj + residual + LN2(l): h += ab@wo + bo; xn = LN(h)
    gemm_ln<true><<<dim3(1, 512), 512, 0, stream>>>(
        ab, base + 196608, d_in[15], (long)l * 256, flags + 15,
        d_in[6], (long)l * 256, flags + 6, d_in[7], (long)l * 256, flags + 7,
        h, xn, 256);
    // FFN1: gelu -> bf16 [N,1024]
    gemm_kernel<1, false><<<dim3(8, 256), 256, 0, stream>>>(
        xn, base + 262144, d_in[17], nullptr, nullptr, (long)l * 1024,
        flags + 17, flags + 17, flags + 17, ffnb, nullptr, 1024, 256);
    if (l == 0) {
      // FFN2 + residual + LN1(l1): h += ffn; xn = LN(h)
      gemm_ln<true><<<dim3(1, 512), 512, 0, stream>>>(
          ffnb, base + 524288, d_in[19], 0, flags + 19,
          d_in[4], 256, flags + 4, d_in[5], 256, flags + 5, h, xn, 1024);
    } else {
      // final: d_out = h + ffn
      gemm_kernel<4, false><<<dim3(2, 256), 256, 0, stream>>>(
          ffnb, base + 524288, d_in[19], nullptr, nullptr, (long)l * 256,
          flags + 19, flags + 19, flags + 19, h, (float*)d_out, 256, 1024);
    }
  }
}